// Round 6
// baseline (1288.556 us; speedup 1.0000x reference)
//
#include <hip/hip_runtime.h>
#include <hip/hip_bf16.h>

#define B_   4
#define L_   2048
#define DM   512
#define DI   1024
#define NST  16
#define DTR  32
#define ROWS (B_ * L_)   // 8192
#define NCHUNK 32
#define CLEN  (L_ / NCHUNK)   // 64

typedef unsigned short u16;
typedef __attribute__((ext_vector_type(8))) short bf16x8;
typedef __attribute__((ext_vector_type(4))) float f32x4;
typedef __attribute__((ext_vector_type(4))) float float4v;

__device__ __forceinline__ float bf2f(u16 h) {
  union { unsigned int u; float f; } v; v.u = ((unsigned int)h) << 16; return v.f;
}
__device__ __forceinline__ u16 f2bf(float f) {
  union { float f; unsigned int u; } v; v.f = f;
  unsigned int u = v.u;
  if ((u & 0x7fffffffu) > 0x7f800000u) return (u16)((u >> 16) | 0x0040u);
  return (u16)((u + 0x7fffu + ((u >> 16) & 1u)) >> 16);
}
__device__ __forceinline__ float sigmoidf_(float x) { return 1.f / (1.f + __expf(-x)); }

// async global->LDS, 16B per lane; dest = wave-uniform base + lane*16 (m97 pattern)
__device__ __forceinline__ void gload16(const u16* g, u16* l) {
  __builtin_amdgcn_global_load_lds(
      (const __attribute__((address_space(1))) void*)g,
      (__attribute__((address_space(3))) void*)l, 16, 0, 0);
}

// ---------------- f32 -> bf16 weight conversion ----------------
__global__ __launch_bounds__(256) void cvt_k(const float* __restrict__ in,
                                             u16* __restrict__ out, int n4) {
  int i = blockIdx.x * 256 + threadIdx.x;       // n4 = n/4
  if (i >= n4) return;
  float4v v = *(const float4v*)&in[i * 4];
  u16 o[4];
  o[0] = f2bf(v.x); o[1] = f2bf(v.y); o[2] = f2bf(v.z); o[3] = f2bf(v.w);
  *(ulong1*)&out[i * 4] = *(ulong1*)o;
}

// ---------------- embed gather (writes f32 residual) ----------------
__global__ __launch_bounds__(256) void embed_k(const int* __restrict__ ids,
                                               const float* __restrict__ emb,
                                               float* __restrict__ res, int flip) {
  int idx = blockIdx.x * 256 + threadIdx.x;         // ROWS*DM threads
  int c = idx & (DM - 1);
  int row = idx >> 9;
  int b = row >> 11;
  int l = row & (L_ - 1);
  int sl = flip ? (L_ - 1 - l) : l;
  int id = ids[(b << 11) + sl];
  res[idx] = emb[id * DM + c];
}

// ---------------- (res += hid); xn = rmsnorm(res) * w  (bf16 out) ----------------
template <bool ADD>
__global__ __launch_bounds__(256) void addnorm_k(float* __restrict__ res,
                                                 const float* __restrict__ hid,
                                                 const float* __restrict__ w,
                                                 u16* __restrict__ xn) {
  int row = blockIdx.x;
  int tid = threadIdx.x;
  int base = row * DM;
  float x0 = res[base + tid];
  float x1 = res[base + 256 + tid];
  if (ADD) {
    x0 += hid[base + tid];
    x1 += hid[base + 256 + tid];
    res[base + tid] = x0;
    res[base + 256 + tid] = x1;
  }
  float s = x0 * x0 + x1 * x1;
  for (int off = 32; off; off >>= 1) s += __shfl_xor(s, off);
  __shared__ float ps[4];
  if (!(tid & 63)) ps[tid >> 6] = s;
  __syncthreads();
  float tot = ps[0] + ps[1] + ps[2] + ps[3];
  float rs = 1.f / sqrtf(tot / (float)DM + 1e-5f);
  xn[base + tid]       = f2bf(x0 * rs * w[tid]);
  xn[base + 256 + tid] = f2bf(x1 * rs * w[tid + 256]);
}

// ---------------- GEMM: out[m][n] = sum_k A[m][k] * W[n][k] ----------------
// m97-style: linear LDS [rows][32] bf16, global_load_lds 16B staging.
#define EPI_F32  0
#define EPI_BF16 1
#define EPI_BIAS 2

template <int BN, int EPI>
__global__ __launch_bounds__(256) void gemm_bt(const u16* __restrict__ A,
                                               const u16* __restrict__ W,
                                               void* __restrict__ outp,
                                               const float* __restrict__ bias,
                                               int N, int K) {
  constexpr int BM = 128, BK = 32;
  constexpr int NF = BN / 32;                      // n-frags per wave
  __shared__ u16 As[BM * BK];                      // 8 kB, linear
  __shared__ u16 Wsh[BN * BK];
  int tid = threadIdx.x;
  int lane = tid & 63;
  int wv = tid >> 6;
  int wr = wv >> 1, wc = wv & 1;
  int m0 = blockIdx.x * BM, n0 = blockIdx.y * BN;
  f32x4 acc[4][NF];
#pragma unroll
  for (int i = 0; i < 4; ++i)
#pragma unroll
    for (int j = 0; j < NF; ++j) acc[i][j] = (f32x4){0.f, 0.f, 0.f, 0.f};
  int rr = lane & 15;
  int kk = (lane >> 4) << 3;
  int l4 = lane >> 2;          // 0..15: row within 16-row chunk
  int c8 = (lane & 3) << 3;    // 0,8,16,24: k-col (u16)
  const u16* Ag = A + (size_t)(m0 + l4) * K + c8;
  const u16* Wg = W + (size_t)(n0 + l4) * K + c8;
  for (int k0 = 0; k0 < K; k0 += BK) {
    gload16(Ag + (size_t)(wv * 16) * K + k0, &As[wv * 512]);
    gload16(Ag + (size_t)((wv + 4) * 16) * K + k0, &As[(wv + 4) * 512]);
    gload16(Wg + (size_t)(wv * 16) * K + k0, &Wsh[wv * 512]);
    if (BN == 128)
      gload16(Wg + (size_t)((wv + 4) * 16) * K + k0, &Wsh[(wv + 4) * 512]);
    __syncthreads();     // drains vmcnt -> LDS tiles complete
    bf16x8 af[4], wf[NF];
#pragma unroll
    for (int mi = 0; mi < 4; ++mi)
      af[mi] = *(bf16x8*)&As[(wr * 64 + mi * 16 + rr) * BK + kk];
#pragma unroll
    for (int ni = 0; ni < NF; ++ni)
      wf[ni] = *(bf16x8*)&Wsh[(wc * (BN / 2) + ni * 16 + rr) * BK + kk];
#pragma unroll
    for (int mi = 0; mi < 4; ++mi)
#pragma unroll
      for (int ni = 0; ni < NF; ++ni)
        acc[mi][ni] = __builtin_amdgcn_mfma_f32_16x16x32_bf16(af[mi], wf[ni], acc[mi][ni], 0, 0, 0);
    __syncthreads();
  }
  // C/D layout: col = lane&15, row = (lane>>4)*4 + j
  int cr = (lane >> 4) << 2;
  int cc = lane & 15;
#pragma unroll
  for (int mi = 0; mi < 4; ++mi)
#pragma unroll
    for (int ni = 0; ni < NF; ++ni) {
      int row = m0 + wr * 64 + mi * 16 + cr;
      int col = n0 + wc * (BN / 2) + ni * 16 + cc;
      float bv = (EPI == EPI_BIAS) ? bias[col] : 0.f;
#pragma unroll
      for (int j = 0; j < 4; ++j) {
        float v = acc[mi][ni][j] + bv;
        if (EPI == EPI_BF16)
          ((u16*)outp)[(size_t)(row + j) * N + col] = f2bf(v);
        else
          ((float*)outp)[(size_t)(row + j) * N + col] = v;
      }
    }
}

// ---------------- depthwise causal conv (k=4) + bias + SiLU (bf16 out) ----------------
__global__ __launch_bounds__(256) void conv_k(const u16* __restrict__ xz,
                                              const float* __restrict__ cw,
                                              const float* __restrict__ cb,
                                              u16* __restrict__ uh) {
  int idx = blockIdx.x * 256 + threadIdx.x;        // ROWS*DI
  int c = idx & (DI - 1);
  int row = idx >> 10;
  int l = row & (L_ - 1);
  float acc = cb[c];
#pragma unroll
  for (int j = 0; j < 4; ++j) {
    int ls = l + j - 3;
    if (ls >= 0)
      acc += bf2f(xz[(size_t)(row + j - 3) * (2 * DI) + c]) * cw[c * 4 + j];
  }
  float s = acc * sigmoidf_(acc);
  uh[idx] = f2bf(s);
}

// ---------------- chunk-parallel selective scan (1 thread = 1 channel, 16 states in regs) ----
// dt-projection + softplus fused; xdbl tile staged in LDS; u read as bf16.
// pass 1: local scan from h=0 over chunk -> store decay exp(A*S) + local end state
__global__ __launch_bounds__(256) void scan1_k(const u16* __restrict__ uh,
                                               const float* __restrict__ xdbl,
                                               const float* __restrict__ dtw,
                                               const float* __restrict__ dtb,
                                               const float* __restrict__ alog,
                                               float* __restrict__ chk) {
  __shared__ float xs[CLEN][64];                  // 16 kB
  int blk = blockIdx.x;            // B*NCHUNK*(DI/256) = 512
  int db = blk & 3;
  int c  = (blk >> 2) & (NCHUNK - 1);
  int b  = blk >> 7;
  int d  = db * 256 + threadIdx.x;
  int t0 = c * CLEN;
  {
    const float4v* src = (const float4v*)(xdbl + ((size_t)b * L_ + t0) * 64);
    float4v* dst = (float4v*)&xs[0][0];
#pragma unroll
    for (int i = 0; i < 4; ++i) dst[threadIdx.x + i * 256] = src[threadIdx.x + i * 256];
  }
  float wv[DTR];
#pragma unroll
  for (int k = 0; k < DTR; k += 4) {
    float4v v = *(const float4v*)&dtw[(size_t)d * DTR + k];
    wv[k] = v.x; wv[k + 1] = v.y; wv[k + 2] = v.z; wv[k + 3] = v.w;
  }
  float bias = dtb[d];
  float A[NST], h[NST];
#pragma unroll
  for (int n = 0; n < NST; ++n) {
    A[n] = -__expf(alog[d * NST + n]);
    h[n] = 0.f;
  }
  __syncthreads();
  float S = 0.f;
  size_t ubase = ((size_t)b * L_ + t0) * DI + d;
  for (int t = 0; t < CLEN; ++t) {
    float a = bias;
#pragma unroll
    for (int k4 = 0; k4 < 8; ++k4) {
      float4v xv = *(const float4v*)&xs[t][k4 * 4];
      a += xv.x * wv[k4 * 4] + xv.y * wv[k4 * 4 + 1] + xv.z * wv[k4 * 4 + 2] + xv.w * wv[k4 * 4 + 3];
    }
    float dtv = (a > 20.f) ? a : log1pf(__expf(a));
    float uv = bf2f(uh[ubase]);
    float du = dtv * uv;
    S += dtv;
#pragma unroll
    for (int n = 0; n < NST; ++n)
      h[n] = __expf(dtv * A[n]) * h[n] + du * xs[t][DTR + n];
    ubase += DI;
  }
  const size_t H = (size_t)B_ * NCHUNK * DI * NST;
  size_t idx = ((size_t)(b * NCHUNK + c) * DI + d) * NST;
#pragma unroll
  for (int n = 0; n < NST; ++n) {
    chk[idx + n]     = __expf(A[n] * S);
    chk[H + idx + n] = h[n];
  }
}

// pass 2: per (b,d,n): sequential combine over chunks; overwrite chk_h with start states
__global__ __launch_bounds__(256) void scan2_k(float* __restrict__ chk) {
  int j = blockIdx.x * 256 + threadIdx.x;   // 65536 = B*DI*NST
  int n = j & 15;
  int d = (j >> 4) & (DI - 1);
  int b = j >> 14;
  const size_t H = (size_t)B_ * NCHUNK * DI * NST;
  float h = 0.f;
  for (int c = 0; c < NCHUNK; ++c) {
    size_t idx = ((size_t)(b * NCHUNK + c) * DI + d) * NST + n;
    float a = chk[idx];
    float hl = chk[H + idx];
    chk[H + idx] = h;               // start state for this chunk
    h = a * h + hl;
  }
}

// pass 3: re-run chunk from true start state; fused gate -> bf16 yg
__global__ __launch_bounds__(256) void scan3_k(const u16* __restrict__ uh,
                                               const float* __restrict__ xdbl,
                                               const float* __restrict__ dtw,
                                               const float* __restrict__ dtb,
                                               const float* __restrict__ alog,
                                               const float* __restrict__ dvec,
                                               const float* __restrict__ chk,
                                               const u16* __restrict__ xz,
                                               u16* __restrict__ yg) {
  __shared__ float xs[CLEN][64];                  // 16 kB
  int blk = blockIdx.x;            // 512
  int db = blk & 3;
  int c  = (blk >> 2) & (NCHUNK - 1);
  int b  = blk >> 7;
  int d  = db * 256 + threadIdx.x;
  int t0 = c * CLEN;
  {
    const float4v* src = (const float4v*)(xdbl + ((size_t)b * L_ + t0) * 64);
    float4v* dst = (float4v*)&xs[0][0];
#pragma unroll
    for (int i = 0; i < 4; ++i) dst[threadIdx.x + i * 256] = src[threadIdx.x + i * 256];
  }
  float wv[DTR];
#pragma unroll
  for (int k = 0; k < DTR; k += 4) {
    float4v v = *(const float4v*)&dtw[(size_t)d * DTR + k];
    wv[k] = v.x; wv[k + 1] = v.y; wv[k + 2] = v.z; wv[k + 3] = v.w;
  }
  float bias = dtb[d];
  const size_t H = (size_t)B_ * NCHUNK * DI * NST;
  size_t cidx = ((size_t)(b * NCHUNK + c) * DI + d) * NST;
  float A[NST], h[NST];
#pragma unroll
  for (int n = 0; n < NST; ++n) {
    A[n] = -__expf(alog[d * NST + n]);
    h[n] = chk[H + cidx + n];
  }
  float Dv = dvec[d];
  __syncthreads();
  size_t ubase = ((size_t)b * L_ + t0) * DI + d;
  size_t zbase = ((size_t)b * L_ + t0) * (2 * DI) + DI + d;
  for (int t = 0; t < CLEN; ++t) {
    float a = bias;
#pragma unroll
    for (int k4 = 0; k4 < 8; ++k4) {
      float4v xv = *(const float4v*)&xs[t][k4 * 4];
      a += xv.x * wv[k4 * 4] + xv.y * wv[k4 * 4 + 1] + xv.z * wv[k4 * 4 + 2] + xv.w * wv[k4 * 4 + 3];
    }
    float dtv = (a > 20.f) ? a : log1pf(__expf(a));
    float uv = bf2f(uh[ubase]);
    float du = dtv * uv;
    float acc = 0.f;
#pragma unroll
    for (int n = 0; n < NST; ++n) {
      h[n] = __expf(dtv * A[n]) * h[n] + du * xs[t][DTR + n];
      acc += h[n] * xs[t][DTR + NST + n];
    }
    float y = acc + uv * Dv;
    float z = bf2f(xz[zbase]);
    yg[ubase] = f2bf(y * z * sigmoidf_(z));
    ubase += DI; zbase += 2 * DI;
  }
}

// ---------------- final rmsnorm(hid+res) -> concat buffer (with flip for dir 1) ----------------
__global__ __launch_bounds__(256) void fincat_k(const float* __restrict__ hid,
                                                const float* __restrict__ res,
                                                const float* __restrict__ w,
                                                u16* __restrict__ cat, int dir) {
  int row = blockIdx.x;
  int tid = threadIdx.x;
  int base = row * DM;
  float x0 = hid[base + tid] + res[base + tid];
  float x1 = hid[base + 256 + tid] + res[base + 256 + tid];
  float s = x0 * x0 + x1 * x1;
  for (int off = 32; off; off >>= 1) s += __shfl_xor(s, off);
  __shared__ float ps[4];
  if (!(tid & 63)) ps[tid >> 6] = s;
  __syncthreads();
  float tot = ps[0] + ps[1] + ps[2] + ps[3];
  float rs = 1.f / sqrtf(tot / (float)DM + 1e-5f);
  int b = row >> 11, l = row & (L_ - 1);
  size_t drow = dir ? ((size_t)(b << 11) + (L_ - 1 - l)) : (size_t)row;
  size_t obase = drow * (2 * DM) + (size_t)dir * DM;
  cat[obase + tid]       = f2bf(x0 * rs * w[tid]);
  cat[obase + 256 + tid] = f2bf(x1 * rs * w[tid + 256]);
}

extern "C" void kernel_launch(void* const* d_in, const int* in_sizes, int n_in,
                              void* d_out, int out_size, void* d_ws, size_t ws_size,
                              hipStream_t stream) {
  const int*   ids      = (const int*)d_in[0];
  const float* embed    = (const float*)d_in[2];
  const float* in_w     = (const float*)d_in[3];
  const float* conv_w   = (const float*)d_in[4];
  const float* conv_b   = (const float*)d_in[5];
  const float* x_w      = (const float*)d_in[6];
  const float* dt_w     = (const float*)d_in[7];
  const float* dt_bias  = (const float*)d_in[8];
  const float* A_log    = (const float*)d_in[9];
  const float* Dp       = (const float*)d_in[10];
  const float* out_w    = (const float*)d_in[11];
  const float* norm_w   = (const float*)d_in[12];
  const float* norm_f   = (const float*)d_in[13];
  const float* proj_w   = (const float*)d_in[14];
  const float* proj_b   = (const float*)d_in[15];

  char* ws = (char*)d_ws;
  size_t off = 0;
  auto alloc = [&](size_t bytes) {
    void* p = ws + off;
    off += (bytes + 255) & ~(size_t)255;
    return p;
  };
  float* res  = (float*)alloc((size_t)ROWS * DM * 4);        // 16.8 MB
  float* hid  = (float*)alloc((size_t)ROWS * DM * 4);        // 16.8 MB
  u16*   xnyg = (u16*)alloc((size_t)ROWS * DI * 2);          // 16.8 MB (xn | yg)
  u16*   xz   = (u16*)alloc((size_t)ROWS * 2 * DI * 2);      // 33.6 MB
  u16*   u_h  = (u16*)alloc((size_t)ROWS * DI * 2);          // 16.8 MB
  float* xdbl = (float*)alloc((size_t)ROWS * 64 * 4);        //  2.1 MB
  float* chk  = (float*)alloc((size_t)2 * B_ * NCHUNK * DI * NST * 4);  // 16.8 MB
  u16*   cat  = (u16*)alloc((size_t)ROWS * 2 * DM * 2);      // 16.8 MB
  const int N_IN  = 4 * 2 * DI * DM;   // 4,194,304
  const int N_XW  = 4 * 64 * DI;       //   262,144
  const int N_OW  = 4 * DM * DI;       // 2,097,152
  const int N_PW  = DM * 2 * DM;       //   524,288
  u16* in_wb  = (u16*)alloc((size_t)N_IN * 2);               //  8.4 MB
  u16* x_wb   = (u16*)alloc((size_t)N_XW * 2);               //  0.5 MB
  u16* out_wb = (u16*)alloc((size_t)N_OW * 2);               //  4.2 MB
  u16* pr_wb  = (u16*)alloc((size_t)N_PW * 2);               //  1.0 MB
  if (off > ws_size) return;

  cvt_k<<<(N_IN / 4 + 255) / 256, 256, 0, stream>>>(in_w, in_wb, N_IN / 4);
  cvt_k<<<(N_XW / 4 + 255) / 256, 256, 0, stream>>>(x_w, x_wb, N_XW / 4);
  cvt_k<<<(N_OW / 4 + 255) / 256, 256, 0, stream>>>(out_w, out_wb, N_OW / 4);
  cvt_k<<<(N_PW / 4 + 255) / 256, 256, 0, stream>>>(proj_w, pr_wb, N_PW / 4);

  for (int d = 0; d < 2; ++d) {
    embed_k<<<ROWS * DM / 256, 256, 0, stream>>>(ids, embed + (size_t)d * 128 * DM, res, d);
    for (int i = 0; i < 2; ++i) {
      int li = d * 2 + i;
      if (i == 0)
        addnorm_k<false><<<ROWS, 256, 0, stream>>>(res, hid, norm_w + (size_t)li * DM, xnyg);
      else
        addnorm_k<true><<<ROWS, 256, 0, stream>>>(res, hid, norm_w + (size_t)li * DM, xnyg);
      gemm_bt<128, EPI_BF16><<<dim3(ROWS / 128, 16), 256, 0, stream>>>(
          xnyg, in_wb + (size_t)li * 2 * DI * DM, xz, nullptr, 2 * DI, DM);
      conv_k<<<ROWS * DI / 256, 256, 0, stream>>>(
          xz, conv_w + (size_t)li * DI * 4, conv_b + (size_t)li * DI, u_h);
      gemm_bt<64, EPI_F32><<<dim3(ROWS / 128, 1), 256, 0, stream>>>(
          u_h, x_wb + (size_t)li * 64 * DI, xdbl, nullptr, 64, DI);
      scan1_k<<<B_ * NCHUNK * (DI / 256), 256, 0, stream>>>(
          u_h, xdbl, dt_w + (size_t)li * DI * DTR, dt_bias + (size_t)li * DI,
          A_log + (size_t)li * DI * NST, chk);
      scan2_k<<<(B_ * DI * NST) / 256, 256, 0, stream>>>(chk);
      scan3_k<<<B_ * NCHUNK * (DI / 256), 256, 0, stream>>>(
          u_h, xdbl, dt_w + (size_t)li * DI * DTR, dt_bias + (size_t)li * DI,
          A_log + (size_t)li * DI * NST, Dp + (size_t)li * DI, chk, xz, xnyg);
      gemm_bt<64, EPI_F32><<<dim3(ROWS / 128, DM / 64), 256, 0, stream>>>(
          xnyg, out_wb + (size_t)li * DM * DI, hid, nullptr, DM, DI);
    }
    fincat_k<<<ROWS, 256, 0, stream>>>(hid, res, norm_f + (size_t)d * DM, cat, d);
  }
  gemm_bt<64, EPI_BIAS><<<dim3(ROWS / 128, DM / 64), 256, 0, stream>>>(
      cat, pr_wb, (float*)d_out, proj_b, DM, DI);
}

// Round 7
// 1115.073 us; speedup vs baseline: 1.1556x; 1.1556x over previous
//
#include <hip/hip_runtime.h>
#include <hip/hip_bf16.h>

#define B_   4
#define L_   2048
#define DM   512
#define DI   1024
#define NST  16
#define DTR  32
#define ROWS (B_ * L_)   // 8192
#define NCHUNK 64
#define CLEN  (L_ / NCHUNK)   // 32
#define LN2R 1.4426950408889634f

typedef unsigned short u16;
typedef __attribute__((ext_vector_type(8))) short bf16x8;
typedef __attribute__((ext_vector_type(4))) float f32x4;
typedef __attribute__((ext_vector_type(4))) float float4v;

__device__ __forceinline__ float bf2f(u16 h) {
  union { unsigned int u; float f; } v; v.u = ((unsigned int)h) << 16; return v.f;
}
__device__ __forceinline__ u16 f2bf(float f) {
  union { float f; unsigned int u; } v; v.f = f;
  unsigned int u = v.u;
  if ((u & 0x7fffffffu) > 0x7f800000u) return (u16)((u >> 16) | 0x0040u);
  return (u16)((u + 0x7fffu + ((u >> 16) & 1u)) >> 16);
}
__device__ __forceinline__ float sigmoidf_(float x) { return 1.f / (1.f + __expf(-x)); }

// async global->LDS, 16B per lane; dest = wave-uniform base + lane*16 (m97 pattern)
__device__ __forceinline__ void gload16(const u16* g, u16* l) {
  __builtin_amdgcn_global_load_lds(
      (const __attribute__((address_space(1))) void*)g,
      (__attribute__((address_space(3))) void*)l, 16, 0, 0);
}

// ---------------- f32 -> bf16 weight conversion ----------------
__global__ __launch_bounds__(256) void cvt_k(const float* __restrict__ in,
                                             u16* __restrict__ out, int n4) {
  int i = blockIdx.x * 256 + threadIdx.x;       // n4 = n/4
  if (i >= n4) return;
  float4v v = *(const float4v*)&in[i * 4];
  u16 o[4];
  o[0] = f2bf(v.x); o[1] = f2bf(v.y); o[2] = f2bf(v.z); o[3] = f2bf(v.w);
  *(ulong1*)&out[i * 4] = *(ulong1*)o;
}

// ---------------- dt_w transpose: [4][DI][DTR] -> [4][DTR][DI] (f32) ----------------
__global__ __launch_bounds__(256) void trp_k(const float* __restrict__ in,
                                             float* __restrict__ out) {
  int o = blockIdx.x * 256 + threadIdx.x;       // 4*DTR*DI = 131072
  int li = o >> 15;
  int k = (o >> 10) & (DTR - 1);
  int d = o & (DI - 1);
  out[o] = in[((size_t)li * DI + d) * DTR + k];
}

// ---------------- embed gather (writes f32 residual) ----------------
__global__ __launch_bounds__(256) void embed_k(const int* __restrict__ ids,
                                               const float* __restrict__ emb,
                                               float* __restrict__ res, int flip) {
  int idx = blockIdx.x * 256 + threadIdx.x;         // ROWS*DM threads
  int c = idx & (DM - 1);
  int row = idx >> 9;
  int b = row >> 11;
  int l = row & (L_ - 1);
  int sl = flip ? (L_ - 1 - l) : l;
  int id = ids[(b << 11) + sl];
  res[idx] = emb[id * DM + c];
}

// ---------------- (res += hid); xn = rmsnorm(res) * w  (bf16 out) ----------------
template <bool ADD>
__global__ __launch_bounds__(256) void addnorm_k(float* __restrict__ res,
                                                 const float* __restrict__ hid,
                                                 const float* __restrict__ w,
                                                 u16* __restrict__ xn) {
  int row = blockIdx.x;
  int tid = threadIdx.x;
  int base = row * DM;
  float x0 = res[base + tid];
  float x1 = res[base + 256 + tid];
  if (ADD) {
    x0 += hid[base + tid];
    x1 += hid[base + 256 + tid];
    res[base + tid] = x0;
    res[base + 256 + tid] = x1;
  }
  float s = x0 * x0 + x1 * x1;
  for (int off = 32; off; off >>= 1) s += __shfl_xor(s, off);
  __shared__ float ps[4];
  if (!(tid & 63)) ps[tid >> 6] = s;
  __syncthreads();
  float tot = ps[0] + ps[1] + ps[2] + ps[3];
  float rs = 1.f / sqrtf(tot / (float)DM + 1e-5f);
  xn[base + tid]       = f2bf(x0 * rs * w[tid]);
  xn[base + 256 + tid] = f2bf(x1 * rs * w[tid + 256]);
}

// ---------------- GEMM: out[m][n] = sum_k A[m][k] * W[n][k] ----------------
// m97-style: linear LDS [rows][32] bf16, global_load_lds 16B staging.
#define EPI_F32  0
#define EPI_BF16 1
#define EPI_BIAS 2

template <int BN, int EPI>
__global__ __launch_bounds__(256) void gemm_bt(const u16* __restrict__ A,
                                               const u16* __restrict__ W,
                                               void* __restrict__ outp,
                                               const float* __restrict__ bias,
                                               int N, int K) {
  constexpr int BM = 128, BK = 32;
  constexpr int NF = BN / 32;                      // n-frags per wave
  __shared__ u16 As[BM * BK];                      // 8 kB, linear
  __shared__ u16 Wsh[BN * BK];
  int tid = threadIdx.x;
  int lane = tid & 63;
  int wv = tid >> 6;
  int wr = wv >> 1, wc = wv & 1;
  int m0 = blockIdx.x * BM, n0 = blockIdx.y * BN;
  f32x4 acc[4][NF];
#pragma unroll
  for (int i = 0; i < 4; ++i)
#pragma unroll
    for (int j = 0; j < NF; ++j) acc[i][j] = (f32x4){0.f, 0.f, 0.f, 0.f};
  int rr = lane & 15;
  int kk = (lane >> 4) << 3;
  int l4 = lane >> 2;          // 0..15: row within 16-row chunk
  int c8 = (lane & 3) << 3;    // 0,8,16,24: k-col (u16)
  const u16* Ag = A + (size_t)(m0 + l4) * K + c8;
  const u16* Wg = W + (size_t)(n0 + l4) * K + c8;
  for (int k0 = 0; k0 < K; k0 += BK) {
    gload16(Ag + (size_t)(wv * 16) * K + k0, &As[wv * 512]);
    gload16(Ag + (size_t)((wv + 4) * 16) * K + k0, &As[(wv + 4) * 512]);
    gload16(Wg + (size_t)(wv * 16) * K + k0, &Wsh[wv * 512]);
    if (BN == 128)
      gload16(Wg + (size_t)((wv + 4) * 16) * K + k0, &Wsh[(wv + 4) * 512]);
    __syncthreads();     // drains vmcnt -> LDS tiles complete
    bf16x8 af[4], wf[NF];
#pragma unroll
    for (int mi = 0; mi < 4; ++mi)
      af[mi] = *(bf16x8*)&As[(wr * 64 + mi * 16 + rr) * BK + kk];
#pragma unroll
    for (int ni = 0; ni < NF; ++ni)
      wf[ni] = *(bf16x8*)&Wsh[(wc * (BN / 2) + ni * 16 + rr) * BK + kk];
#pragma unroll
    for (int mi = 0; mi < 4; ++mi)
#pragma unroll
      for (int ni = 0; ni < NF; ++ni)
        acc[mi][ni] = __builtin_amdgcn_mfma_f32_16x16x32_bf16(af[mi], wf[ni], acc[mi][ni], 0, 0, 0);
    __syncthreads();
  }
  // C/D layout: col = lane&15, row = (lane>>4)*4 + j
  int cr = (lane >> 4) << 2;
  int cc = lane & 15;
#pragma unroll
  for (int mi = 0; mi < 4; ++mi)
#pragma unroll
    for (int ni = 0; ni < NF; ++ni) {
      int row = m0 + wr * 64 + mi * 16 + cr;
      int col = n0 + wc * (BN / 2) + ni * 16 + cc;
      float bv = (EPI == EPI_BIAS) ? bias[col] : 0.f;
#pragma unroll
      for (int j = 0; j < 4; ++j) {
        float v = acc[mi][ni][j] + bv;
        if (EPI == EPI_BF16)
          ((u16*)outp)[(size_t)(row + j) * N + col] = f2bf(v);
        else
          ((float*)outp)[(size_t)(row + j) * N + col] = v;
      }
    }
}

// ---------------- depthwise causal conv (k=4) + bias + SiLU (bf16 out) ----------------
__global__ __launch_bounds__(256) void conv_k(const u16* __restrict__ xz,
                                              const float* __restrict__ cw,
                                              const float* __restrict__ cb,
                                              u16* __restrict__ uh) {
  int idx = blockIdx.x * 256 + threadIdx.x;        // ROWS*DI
  int c = idx & (DI - 1);
  int row = idx >> 10;
  int l = row & (L_ - 1);
  float acc = cb[c];
#pragma unroll
  for (int j = 0; j < 4; ++j) {
    int ls = l + j - 3;
    if (ls >= 0)
      acc += bf2f(xz[(size_t)(row + j - 3) * (2 * DI) + c]) * cw[c * 4 + j];
  }
  float s = acc * sigmoidf_(acc);
  uh[idx] = f2bf(s);
}

// ---------------- dt = softplus(xdbl[:, :32] @ dtw^T + dtb), f32 out ----------------
// dtw_t: [DTR][DI] (k-major, transposed) -> coalesced weight loads.
__global__ __launch_bounds__(256) void dtk(const float* __restrict__ xdbl,
                                           const float* __restrict__ dtw_t,
                                           const float* __restrict__ dtb,
                                           float* __restrict__ dtf) {
  __shared__ float xs[32][DTR];                   // 4 kB: 32 rows of x
  int rg = blockIdx.x >> 2;                       // row group (32 rows)
  int cg = blockIdx.x & 3;
  int tid = threadIdx.x;
  int c = cg * 256 + tid;
  {
    int r = tid >> 3, kk = (tid & 7) << 2;
    *(float4v*)&xs[r][kk] = *(const float4v*)&xdbl[(size_t)(rg * 32 + r) * 64 + kk];
  }
  float w[DTR];
#pragma unroll
  for (int k = 0; k < DTR; ++k) w[k] = dtw_t[(size_t)k * DI + c];
  float bias = dtb[c];
  __syncthreads();
#pragma unroll 4
  for (int r = 0; r < 32; ++r) {
    float a = bias;
#pragma unroll
    for (int k4 = 0; k4 < 8; ++k4) {
      float4v xv = *(const float4v*)&xs[r][k4 * 4];
      a += xv.x * w[k4 * 4] + xv.y * w[k4 * 4 + 1] + xv.z * w[k4 * 4 + 2] + xv.w * w[k4 * 4 + 3];
    }
    float sp = (a > 15.f) ? a : __logf(1.f + __expf(a));
    dtf[(size_t)(rg * 32 + r) * DI + c] = sp;
  }
}

// ---------------- chunk-parallel selective scan (1 thread = 1 channel, 16 states in regs) ----
// pass 1: local scan from h=0 over chunk -> store decay exp2(A2*S) + local end state
__global__ __launch_bounds__(256) void scan1_k(const u16* __restrict__ uh,
                                               const float* __restrict__ dtf,
                                               const float* __restrict__ xdbl,
                                               const float* __restrict__ alog,
                                               float* __restrict__ chk) {
  __shared__ float xs[CLEN][64];                  // 8 kB
  int blk = blockIdx.x;            // B*NCHUNK*(DI/256) = 4*64*4 = 1024
  int db = blk & 3;
  int c  = (blk >> 2) & (NCHUNK - 1);
  int b  = blk >> 8;
  int tid = threadIdx.x;
  int d  = db * 256 + tid;
  int t0 = c * CLEN;
  {
    const float4v* src = (const float4v*)(xdbl + ((size_t)b * L_ + t0) * 64);
    float4v* dst = (float4v*)&xs[0][0];
    dst[tid] = src[tid];
    dst[tid + 256] = src[tid + 256];
  }
  float A2[NST], h[NST];
#pragma unroll
  for (int n = 0; n < NST; ++n) {
    A2[n] = -__expf(alog[d * NST + n]) * LN2R;
    h[n] = 0.f;
  }
  __syncthreads();
  float S = 0.f;
  size_t ubase = ((size_t)b * L_ + t0) * DI + d;
  for (int t = 0; t < CLEN; ++t) {
    float dtv = dtf[ubase];
    float du  = dtv * bf2f(uh[ubase]);
    S += dtv;
    const float4v* xr = (const float4v*)&xs[t][DTR];
    float4v bv0 = xr[0], bv1 = xr[1], bv2 = xr[2], bv3 = xr[3];
#pragma unroll
    for (int q = 0; q < 4; ++q) {
      float4v bv = (q == 0) ? bv0 : (q == 1) ? bv1 : (q == 2) ? bv2 : bv3;
#pragma unroll
      for (int j = 0; j < 4; ++j) {
        int n = q * 4 + j;
        h[n] = exp2f(dtv * A2[n]) * h[n] + du * bv[j];
      }
    }
    ubase += DI;
  }
  const size_t H = (size_t)B_ * NCHUNK * DI * NST;
  size_t idx = ((size_t)(b * NCHUNK + c) * DI + d) * NST;
#pragma unroll
  for (int n = 0; n < NST; ++n) {
    chk[idx + n]     = exp2f(A2[n] * S);
    chk[H + idx + n] = h[n];
  }
}

// pass 2: per (b,d,n): sequential combine over chunks; overwrite chk_h with start states
__global__ __launch_bounds__(256) void scan2_k(float* __restrict__ chk) {
  int j = blockIdx.x * 256 + threadIdx.x;   // 65536 = B*DI*NST
  int n = j & 15;
  int d = (j >> 4) & (DI - 1);
  int b = j >> 14;
  const size_t H = (size_t)B_ * NCHUNK * DI * NST;
  float h = 0.f;
  for (int c = 0; c < NCHUNK; ++c) {
    size_t idx = ((size_t)(b * NCHUNK + c) * DI + d) * NST + n;
    float a = chk[idx];
    float hl = chk[H + idx];
    chk[H + idx] = h;               // start state for this chunk
    h = a * h + hl;
  }
}

// pass 3: re-run chunk from true start state; fused gate -> bf16 yg
__global__ __launch_bounds__(256) void scan3_k(const u16* __restrict__ uh,
                                               const float* __restrict__ dtf,
                                               const float* __restrict__ xdbl,
                                               const float* __restrict__ alog,
                                               const float* __restrict__ dvec,
                                               const float* __restrict__ chk,
                                               const u16* __restrict__ xz,
                                               u16* __restrict__ yg) {
  __shared__ float xs[CLEN][64];                  // 8 kB
  int blk = blockIdx.x;            // 1024
  int db = blk & 3;
  int c  = (blk >> 2) & (NCHUNK - 1);
  int b  = blk >> 8;
  int tid = threadIdx.x;
  int d  = db * 256 + tid;
  int t0 = c * CLEN;
  {
    const float4v* src = (const float4v*)(xdbl + ((size_t)b * L_ + t0) * 64);
    float4v* dst = (float4v*)&xs[0][0];
    dst[tid] = src[tid];
    dst[tid + 256] = src[tid + 256];
  }
  const size_t H = (size_t)B_ * NCHUNK * DI * NST;
  size_t cidx = ((size_t)(b * NCHUNK + c) * DI + d) * NST;
  float A2[NST], h[NST];
#pragma unroll
  for (int n = 0; n < NST; ++n) {
    A2[n] = -__expf(alog[d * NST + n]) * LN2R;
    h[n] = chk[H + cidx + n];
  }
  float Dv = dvec[d];
  __syncthreads();
  size_t ubase = ((size_t)b * L_ + t0) * DI + d;
  size_t zbase = ((size_t)b * L_ + t0) * (2 * DI) + DI + d;
  for (int t = 0; t < CLEN; ++t) {
    float dtv = dtf[ubase];
    float uv  = bf2f(uh[ubase]);
    float du  = dtv * uv;
    const float4v* xr = (const float4v*)&xs[t][DTR];
    float4v bv0 = xr[0], bv1 = xr[1], bv2 = xr[2], bv3 = xr[3];
    float4v cv0 = xr[4], cv1 = xr[5], cv2 = xr[6], cv3 = xr[7];
    float acc = 0.f;
#pragma unroll
    for (int q = 0; q < 4; ++q) {
      float4v bv = (q == 0) ? bv0 : (q == 1) ? bv1 : (q == 2) ? bv2 : bv3;
      float4v cv = (q == 0) ? cv0 : (q == 1) ? cv1 : (q == 2) ? cv2 : cv3;
#pragma unroll
      for (int j = 0; j < 4; ++j) {
        int n = q * 4 + j;
        h[n] = exp2f(dtv * A2[n]) * h[n] + du * bv[j];
        acc += h[n] * cv[j];
      }
    }
    float y = acc + uv * Dv;
    float z = bf2f(xz[zbase]);
    yg[ubase] = f2bf(y * z * sigmoidf_(z));
    ubase += DI; zbase += 2 * DI;
  }
}

// ---------------- final rmsnorm(hid+res) -> concat buffer (with flip for dir 1) ----------------
__global__ __launch_bounds__(256) void fincat_k(const float* __restrict__ hid,
                                                const float* __restrict__ res,
                                                const float* __restrict__ w,
                                                u16* __restrict__ cat, int dir) {
  int row = blockIdx.x;
  int tid = threadIdx.x;
  int base = row * DM;
  float x0 = hid[base + tid] + res[base + tid];
  float x1 = hid[base + 256 + tid] + res[base + 256 + tid];
  float s = x0 * x0 + x1 * x1;
  for (int off = 32; off; off >>= 1) s += __shfl_xor(s, off);
  __shared__ float ps[4];
  if (!(tid & 63)) ps[tid >> 6] = s;
  __syncthreads();
  float tot = ps[0] + ps[1] + ps[2] + ps[3];
  float rs = 1.f / sqrtf(tot / (float)DM + 1e-5f);
  int b = row >> 11, l = row & (L_ - 1);
  size_t drow = dir ? ((size_t)(b << 11) + (L_ - 1 - l)) : (size_t)row;
  size_t obase = drow * (2 * DM) + (size_t)dir * DM;
  cat[obase + tid]       = f2bf(x0 * rs * w[tid]);
  cat[obase + 256 + tid] = f2bf(x1 * rs * w[tid + 256]);
}

extern "C" void kernel_launch(void* const* d_in, const int* in_sizes, int n_in,
                              void* d_out, int out_size, void* d_ws, size_t ws_size,
                              hipStream_t stream) {
  const int*   ids      = (const int*)d_in[0];
  const float* embed    = (const float*)d_in[2];
  const float* in_w     = (const float*)d_in[3];
  const float* conv_w   = (const float*)d_in[4];
  const float* conv_b   = (const float*)d_in[5];
  const float* x_w      = (const float*)d_in[6];
  const float* dt_w     = (const float*)d_in[7];
  const float* dt_bias  = (const float*)d_in[8];
  const float* A_log    = (const float*)d_in[9];
  const float* Dp       = (const float*)d_in[10];
  const float* out_w    = (const float*)d_in[11];
  const float* norm_w   = (const float*)d_in[12];
  const float* norm_f   = (const float*)d_in[13];
  const float* proj_w   = (const float*)d_in[14];
  const float* proj_b   = (const float*)d_in[15];

  char* ws = (char*)d_ws;
  size_t off = 0;
  auto alloc = [&](size_t bytes) {
    void* p = ws + off;
    off += (bytes + 255) & ~(size_t)255;
    return p;
  };
  float* res  = (float*)alloc((size_t)ROWS * DM * 4);        // 16.8 MB
  float* hid  = (float*)alloc((size_t)ROWS * DM * 4);        // 16.8 MB
  u16*   xnyg = (u16*)alloc((size_t)ROWS * DI * 2);          // 16.8 MB (xn | yg)
  u16*   xz   = (u16*)alloc((size_t)ROWS * 2 * DI * 2);      // 33.6 MB
  u16*   u_h  = (u16*)alloc((size_t)ROWS * DI * 2);          // 16.8 MB
  float* xdbl = (float*)alloc((size_t)ROWS * 64 * 4);        //  2.1 MB
  float* dtf  = (float*)alloc((size_t)ROWS * DI * 4);        // 33.6 MB
  float* chk  = (float*)alloc((size_t)2 * B_ * NCHUNK * DI * NST * 4);  // 33.6 MB
  u16*   cat  = (u16*)alloc((size_t)ROWS * 2 * DM * 2);      // 16.8 MB
  const int N_IN  = 4 * 2 * DI * DM;   // 4,194,304
  const int N_XW  = 4 * 64 * DI;       //   262,144
  const int N_OW  = 4 * DM * DI;       // 2,097,152
  const int N_PW  = DM * 2 * DM;       //   524,288
  const int N_DTW = 4 * DTR * DI;      //   131,072
  u16*   in_wb  = (u16*)alloc((size_t)N_IN * 2);             //  8.4 MB
  u16*   x_wb   = (u16*)alloc((size_t)N_XW * 2);             //  0.5 MB
  u16*   out_wb = (u16*)alloc((size_t)N_OW * 2);             //  4.2 MB
  u16*   pr_wb  = (u16*)alloc((size_t)N_PW * 2);             //  1.0 MB
  float* dtw_t  = (float*)alloc((size_t)N_DTW * 4);          //  0.5 MB
  if (off > ws_size) return;

  cvt_k<<<(N_IN / 4 + 255) / 256, 256, 0, stream>>>(in_w, in_wb, N_IN / 4);
  cvt_k<<<(N_XW / 4 + 255) / 256, 256, 0, stream>>>(x_w, x_wb, N_XW / 4);
  cvt_k<<<(N_OW / 4 + 255) / 256, 256, 0, stream>>>(out_w, out_wb, N_OW / 4);
  cvt_k<<<(N_PW / 4 + 255) / 256, 256, 0, stream>>>(proj_w, pr_wb, N_PW / 4);
  trp_k<<<N_DTW / 256, 256, 0, stream>>>(dt_w, dtw_t);

  for (int d = 0; d < 2; ++d) {
    embed_k<<<ROWS * DM / 256, 256, 0, stream>>>(ids, embed + (size_t)d * 128 * DM, res, d);
    for (int i = 0; i < 2; ++i) {
      int li = d * 2 + i;
      if (i == 0)
        addnorm_k<false><<<ROWS, 256, 0, stream>>>(res, hid, norm_w + (size_t)li * DM, xnyg);
      else
        addnorm_k<true><<<ROWS, 256, 0, stream>>>(res, hid, norm_w + (size_t)li * DM, xnyg);
      gemm_bt<128, EPI_BF16><<<dim3(ROWS / 128, 16), 256, 0, stream>>>(
          xnyg, in_wb + (size_t)li * 2 * DI * DM, xz, nullptr, 2 * DI, DM);
      conv_k<<<ROWS * DI / 256, 256, 0, stream>>>(
          xz, conv_w + (size_t)li * DI * 4, conv_b + (size_t)li * DI, u_h);
      gemm_bt<64, EPI_F32><<<dim3(ROWS / 128, 1), 256, 0, stream>>>(
          u_h, x_wb + (size_t)li * 64 * DI, xdbl, nullptr, 64, DI);
      dtk<<<dim3((ROWS / 32) * 4), 256, 0, stream>>>(
          xdbl, dtw_t + (size_t)li * DTR * DI, dt_bias + (size_t)li * DI, dtf);
      scan1_k<<<B_ * NCHUNK * (DI / 256), 256, 0, stream>>>(
          u_h, dtf, xdbl, A_log + (size_t)li * DI * NST, chk);
      scan2_k<<<(B_ * DI * NST) / 256, 256, 0, stream>>>(chk);
      scan3_k<<<B_ * NCHUNK * (DI / 256), 256, 0, stream>>>(
          u_h, dtf, xdbl, A_log + (size_t)li * DI * NST, Dp + (size_t)li * DI, chk,
          xz, xnyg);
      gemm_bt<64, EPI_F32><<<dim3(ROWS / 128, DM / 64), 256, 0, stream>>>(
          xnyg, out_wb + (size_t)li * DM * DI, hid, nullptr, DM, DI);
    }
    fincat_k<<<ROWS, 256, 0, stream>>>(hid, res, norm_f + (size_t)d * DM, cat, d);
  }
  gemm_bt<64, EPI_BIAS><<<dim3(ROWS / 128, DM / 64), 256, 0, stream>>>(
      cat, pr_wb, (float*)d_out, proj_b, DM, DI);
}

// Round 8
// 932.341 us; speedup vs baseline: 1.3821x; 1.1960x over previous
//
#include <hip/hip_runtime.h>
#include <hip/hip_bf16.h>

#define B_   4
#define L_   2048
#define DM   512
#define DI   1024
#define NST  16
#define DTR  32
#define ROWS (B_ * L_)   // 8192
#define NCHUNK 64
#define CLEN  (L_ / NCHUNK)   // 32
#define LN2R 1.4426950408889634f

typedef unsigned short u16;
typedef __attribute__((ext_vector_type(8))) short bf16x8;
typedef __attribute__((ext_vector_type(4))) float f32x4;
typedef __attribute__((ext_vector_type(4))) float float4v;
typedef __attribute__((ext_vector_type(2))) float f32x2;

__device__ __forceinline__ float bf2f(u16 h) {
  union { unsigned int u; float f; } v; v.u = ((unsigned int)h) << 16; return v.f;
}
__device__ __forceinline__ u16 f2bf(float f) {
  union { float f; unsigned int u; } v; v.f = f;
  unsigned int u = v.u;
  if ((u & 0x7fffffffu) > 0x7f800000u) return (u16)((u >> 16) | 0x0040u);
  return (u16)((u + 0x7fffu + ((u >> 16) & 1u)) >> 16);
}
__device__ __forceinline__ float sigmoidf_(float x) { return 1.f / (1.f + __expf(-x)); }

// packed f32 ops (MI355X full-rate fp32 = v_pk_*_f32)
__device__ __forceinline__ f32x2 pk_mul(f32x2 a, f32x2 b) {
  f32x2 d; asm("v_pk_mul_f32 %0, %1, %2" : "=v"(d) : "v"(a), "v"(b)); return d;
}
__device__ __forceinline__ f32x2 pk_fma(f32x2 a, f32x2 b, f32x2 c) {
  f32x2 d; asm("v_pk_fma_f32 %0, %1, %2, %3" : "=v"(d) : "v"(a), "v"(b), "v"(c)); return d;
}

// async global->LDS, 16B per lane; dest = wave-uniform base + lane*16 (m97 pattern)
__device__ __forceinline__ void gload16(const u16* g, u16* l) {
  __builtin_amdgcn_global_load_lds(
      (const __attribute__((address_space(1))) void*)g,
      (__attribute__((address_space(3))) void*)l, 16, 0, 0);
}

// ---------------- f32 -> bf16 weight conversion ----------------
__global__ __launch_bounds__(256) void cvt_k(const float* __restrict__ in,
                                             u16* __restrict__ out, int n4) {
  int i = blockIdx.x * 256 + threadIdx.x;       // n4 = n/4
  if (i >= n4) return;
  float4v v = *(const float4v*)&in[i * 4];
  u16 o[4];
  o[0] = f2bf(v.x); o[1] = f2bf(v.y); o[2] = f2bf(v.z); o[3] = f2bf(v.w);
  *(ulong1*)&out[i * 4] = *(ulong1*)o;
}

// ---------------- dt_w transpose: [4][DI][DTR] -> [4][DTR][DI] (f32) ----------------
__global__ __launch_bounds__(256) void trp_k(const float* __restrict__ in,
                                             float* __restrict__ out) {
  int o = blockIdx.x * 256 + threadIdx.x;       // 4*DTR*DI = 131072
  int li = o >> 15;
  int k = (o >> 10) & (DTR - 1);
  int d = o & (DI - 1);
  out[o] = in[((size_t)li * DI + d) * DTR + k];
}

// ---------------- embed gather (writes f32 residual) ----------------
__global__ __launch_bounds__(256) void embed_k(const int* __restrict__ ids,
                                               const float* __restrict__ emb,
                                               float* __restrict__ res, int flip) {
  int idx = blockIdx.x * 256 + threadIdx.x;         // ROWS*DM threads
  int c = idx & (DM - 1);
  int row = idx >> 9;
  int b = row >> 11;
  int l = row & (L_ - 1);
  int sl = flip ? (L_ - 1 - l) : l;
  int id = ids[(b << 11) + sl];
  res[idx] = emb[id * DM + c];
}

// ---------------- (res += hid); xn = rmsnorm(res) * w  (bf16 out) ----------------
template <bool ADD>
__global__ __launch_bounds__(256) void addnorm_k(float* __restrict__ res,
                                                 const float* __restrict__ hid,
                                                 const float* __restrict__ w,
                                                 u16* __restrict__ xn) {
  int row = blockIdx.x;
  int tid = threadIdx.x;
  int base = row * DM;
  float x0 = res[base + tid];
  float x1 = res[base + 256 + tid];
  if (ADD) {
    x0 += hid[base + tid];
    x1 += hid[base + 256 + tid];
    res[base + tid] = x0;
    res[base + 256 + tid] = x1;
  }
  float s = x0 * x0 + x1 * x1;
  for (int off = 32; off; off >>= 1) s += __shfl_xor(s, off);
  __shared__ float ps[4];
  if (!(tid & 63)) ps[tid >> 6] = s;
  __syncthreads();
  float tot = ps[0] + ps[1] + ps[2] + ps[3];
  float rs = 1.f / sqrtf(tot / (float)DM + 1e-5f);
  xn[base + tid]       = f2bf(x0 * rs * w[tid]);
  xn[base + 256 + tid] = f2bf(x1 * rs * w[tid + 256]);
}

// ---------------- GEMM: out[m][n] = sum_k A[m][k] * W[n][k] ----------------
#define EPI_F32  0
#define EPI_BF16 1
#define EPI_BIAS 2

template <int BN, int EPI>
__global__ __launch_bounds__(256) void gemm_bt(const u16* __restrict__ A,
                                               const u16* __restrict__ W,
                                               void* __restrict__ outp,
                                               const float* __restrict__ bias,
                                               int N, int K) {
  constexpr int BM = 128, BK = 32;
  constexpr int NF = BN / 32;                      // n-frags per wave
  __shared__ u16 As[BM * BK];                      // 8 kB, linear
  __shared__ u16 Wsh[BN * BK];
  int tid = threadIdx.x;
  int lane = tid & 63;
  int wv = tid >> 6;
  int wr = wv >> 1, wc = wv & 1;
  int m0 = blockIdx.x * BM, n0 = blockIdx.y * BN;
  f32x4 acc[4][NF];
#pragma unroll
  for (int i = 0; i < 4; ++i)
#pragma unroll
    for (int j = 0; j < NF; ++j) acc[i][j] = (f32x4){0.f, 0.f, 0.f, 0.f};
  int rr = lane & 15;
  int kk = (lane >> 4) << 3;
  int l4 = lane >> 2;          // 0..15: row within 16-row chunk
  int c8 = (lane & 3) << 3;    // 0,8,16,24: k-col (u16)
  const u16* Ag = A + (size_t)(m0 + l4) * K + c8;
  const u16* Wg = W + (size_t)(n0 + l4) * K + c8;
  for (int k0 = 0; k0 < K; k0 += BK) {
    gload16(Ag + (size_t)(wv * 16) * K + k0, &As[wv * 512]);
    gload16(Ag + (size_t)((wv + 4) * 16) * K + k0, &As[(wv + 4) * 512]);
    gload16(Wg + (size_t)(wv * 16) * K + k0, &Wsh[wv * 512]);
    if (BN == 128)
      gload16(Wg + (size_t)((wv + 4) * 16) * K + k0, &Wsh[(wv + 4) * 512]);
    __syncthreads();     // drains vmcnt -> LDS tiles complete
    bf16x8 af[4], wf[NF];
#pragma unroll
    for (int mi = 0; mi < 4; ++mi)
      af[mi] = *(bf16x8*)&As[(wr * 64 + mi * 16 + rr) * BK + kk];
#pragma unroll
    for (int ni = 0; ni < NF; ++ni)
      wf[ni] = *(bf16x8*)&Wsh[(wc * (BN / 2) + ni * 16 + rr) * BK + kk];
#pragma unroll
    for (int mi = 0; mi < 4; ++mi)
#pragma unroll
      for (int ni = 0; ni < NF; ++ni)
        acc[mi][ni] = __builtin_amdgcn_mfma_f32_16x16x32_bf16(af[mi], wf[ni], acc[mi][ni], 0, 0, 0);
    __syncthreads();
  }
  // C/D layout: col = lane&15, row = (lane>>4)*4 + j
  int cr = (lane >> 4) << 2;
  int cc = lane & 15;
#pragma unroll
  for (int mi = 0; mi < 4; ++mi)
#pragma unroll
    for (int ni = 0; ni < NF; ++ni) {
      int row = m0 + wr * 64 + mi * 16 + cr;
      int col = n0 + wc * (BN / 2) + ni * 16 + cc;
      float bv = (EPI == EPI_BIAS) ? bias[col] : 0.f;
#pragma unroll
      for (int j = 0; j < 4; ++j) {
        float v = acc[mi][ni][j] + bv;
        if (EPI == EPI_BF16)
          ((u16*)outp)[(size_t)(row + j) * N + col] = f2bf(v);
        else
          ((float*)outp)[(size_t)(row + j) * N + col] = v;
      }
    }
}

// ---------------- depthwise causal conv (k=4) + bias + SiLU (bf16 out) ----------------
__global__ __launch_bounds__(256) void conv_k(const u16* __restrict__ xz,
                                              const float* __restrict__ cw,
                                              const float* __restrict__ cb,
                                              u16* __restrict__ uh) {
  int idx = blockIdx.x * 256 + threadIdx.x;        // ROWS*DI
  int c = idx & (DI - 1);
  int row = idx >> 10;
  int l = row & (L_ - 1);
  float acc = cb[c];
#pragma unroll
  for (int j = 0; j < 4; ++j) {
    int ls = l + j - 3;
    if (ls >= 0)
      acc += bf2f(xz[(size_t)(row + j - 3) * (2 * DI) + c]) * cw[c * 4 + j];
  }
  float s = acc * sigmoidf_(acc);
  uh[idx] = f2bf(s);
}

// ---------------- dt = softplus(xdbl[:, :32] @ dtw^T + dtb), f32 out ----------------
__global__ __launch_bounds__(256) void dtk(const float* __restrict__ xdbl,
                                           const float* __restrict__ dtw_t,
                                           const float* __restrict__ dtb,
                                           float* __restrict__ dtf) {
  __shared__ float xs[32][DTR];                   // 4 kB: 32 rows of x
  int rg = blockIdx.x >> 2;                       // row group (32 rows)
  int cg = blockIdx.x & 3;
  int tid = threadIdx.x;
  int c = cg * 256 + tid;
  {
    int r = tid >> 3, kk = (tid & 7) << 2;
    *(float4v*)&xs[r][kk] = *(const float4v*)&xdbl[(size_t)(rg * 32 + r) * 64 + kk];
  }
  float w[DTR];
#pragma unroll
  for (int k = 0; k < DTR; ++k) w[k] = dtw_t[(size_t)k * DI + c];
  float bias = dtb[c];
  __syncthreads();
#pragma unroll 4
  for (int r = 0; r < 32; ++r) {
    float a = bias;
#pragma unroll
    for (int k4 = 0; k4 < 8; ++k4) {
      float4v xv = *(const float4v*)&xs[r][k4 * 4];
      a += xv.x * w[k4 * 4] + xv.y * w[k4 * 4 + 1] + xv.z * w[k4 * 4 + 2] + xv.w * w[k4 * 4 + 3];
    }
    float sp = (a > 15.f) ? a : __logf(1.f + __expf(a));
    dtf[(size_t)(rg * 32 + r) * DI + c] = sp;
  }
}

// A-structure check: A[n] == (n+1)*A[0] (true for A_log = log(1..16))
__device__ __forceinline__ bool a_fast(const float* alog, int d, float& a20) {
  a20 = -__expf(alog[d * NST]) * LN2R;
  bool fast = true;
#pragma unroll
  for (int n = 1; n < NST; ++n) {
    float an = -__expf(alog[d * NST + n]) * LN2R;
    fast &= (fabsf(an - (float)(n + 1) * a20) <= 1e-5f * (float)(n + 1) * fabsf(a20));
  }
  return fast;
}

// ---------------- chunk-parallel selective scan ----------------
// pass 1: local scan from h=0 over chunk -> store decay + local end state
__global__ __launch_bounds__(256) void scan1_k(const u16* __restrict__ uh,
                                               const float* __restrict__ dtf,
                                               const float* __restrict__ xdbl,
                                               const float* __restrict__ alog,
                                               float* __restrict__ chk) {
  __shared__ float xs[CLEN][64];                  // 8 kB
  int blk = blockIdx.x;            // B*NCHUNK*(DI/256) = 1024
  int db = blk & 3;
  int c  = (blk >> 2) & (NCHUNK - 1);
  int b  = blk >> 8;
  int tid = threadIdx.x;
  int d  = db * 256 + tid;
  int t0 = c * CLEN;
  {
    const float4v* src = (const float4v*)(xdbl + ((size_t)b * L_ + t0) * 64);
    float4v* dst = (float4v*)&xs[0][0];
    dst[tid] = src[tid];
    dst[tid + 256] = src[tid + 256];
  }
  float a20;
  bool fast = a_fast(alog, d, a20);
  __syncthreads();
  float S = 0.f;
  size_t ubase = ((size_t)b * L_ + t0) * DI + d;
  f32x2 h2[8];
#pragma unroll
  for (int q = 0; q < 8; ++q) h2[q] = (f32x2){0.f, 0.f};
  if (fast) {
    for (int t = 0; t < CLEN; ++t) {
      float dtv = dtf[ubase];
      float du  = dtv * bf2f(uh[ubase]);
      S += dtv;
      float p1 = exp2f(dtv * a20);
      float p2 = p1 * p1;
      f32x2 pw = {p1, p2};
      f32x2 pst = {p2, p2};
      f32x2 du2 = {du, du};
#pragma unroll
      for (int k = 0; k < 4; ++k) {
        f32x4 bv = *(const f32x4*)&xs[t][DTR + k * 4];
        f32x2 blo = __builtin_shufflevector(bv, bv, 0, 1);
        f32x2 bhi = __builtin_shufflevector(bv, bv, 2, 3);
        h2[2 * k]     = pk_fma(pw, h2[2 * k], pk_mul(du2, blo));
        pw = pk_mul(pw, pst);
        h2[2 * k + 1] = pk_fma(pw, h2[2 * k + 1], pk_mul(du2, bhi));
        if (k < 3) pw = pk_mul(pw, pst);
      }
      ubase += DI;
    }
  } else {
    float A2[NST];
#pragma unroll
    for (int n = 0; n < NST; ++n) A2[n] = -__expf(alog[d * NST + n]) * LN2R;
    for (int t = 0; t < CLEN; ++t) {
      float dtv = dtf[ubase];
      float du  = dtv * bf2f(uh[ubase]);
      S += dtv;
#pragma unroll
      for (int q = 0; q < 8; ++q) {
        f32x2 bv = *(const f32x2*)&xs[t][DTR + q * 2];
        f32x2 e = {exp2f(dtv * A2[2 * q]), exp2f(dtv * A2[2 * q + 1])};
        h2[q] = pk_fma(e, h2[q], pk_mul((f32x2){du, du}, bv));
      }
      ubase += DI;
    }
  }
  const size_t H = (size_t)B_ * NCHUNK * DI * NST;
  size_t idx = ((size_t)(b * NCHUNK + c) * DI + d) * NST;
#pragma unroll
  for (int n = 0; n < NST; ++n) {
    float an = -__expf(alog[d * NST + n]) * LN2R;
    chk[idx + n]     = exp2f(an * S);
    chk[H + idx + n] = (n & 1) ? h2[n >> 1].y : h2[n >> 1].x;
  }
}

// pass 2: per (b,d,n): sequential combine over chunks; overwrite chk_h with start states
__global__ __launch_bounds__(256) void scan2_k(float* __restrict__ chk) {
  int j = blockIdx.x * 256 + threadIdx.x;   // 65536 = B*DI*NST
  int n = j & 15;
  int d = (j >> 4) & (DI - 1);
  int b = j >> 14;
  const size_t H = (size_t)B_ * NCHUNK * DI * NST;
  float h = 0.f;
  for (int c = 0; c < NCHUNK; ++c) {
    size_t idx = ((size_t)(b * NCHUNK + c) * DI + d) * NST + n;
    float a = chk[idx];
    float hl = chk[H + idx];
    chk[H + idx] = h;               // start state for this chunk
    h = a * h + hl;
  }
}

// pass 3: re-run chunk from true start state; fused gate -> bf16 yg
__global__ __launch_bounds__(256) void scan3_k(const u16* __restrict__ uh,
                                               const float* __restrict__ dtf,
                                               const float* __restrict__ xdbl,
                                               const float* __restrict__ alog,
                                               const float* __restrict__ dvec,
                                               const float* __restrict__ chk,
                                               const u16* __restrict__ xz,
                                               u16* __restrict__ yg) {
  __shared__ float xs[CLEN][64];                  // 8 kB
  int blk = blockIdx.x;            // 1024
  int db = blk & 3;
  int c  = (blk >> 2) & (NCHUNK - 1);
  int b  = blk >> 8;
  int tid = threadIdx.x;
  int d  = db * 256 + tid;
  int t0 = c * CLEN;
  {
    const float4v* src = (const float4v*)(xdbl + ((size_t)b * L_ + t0) * 64);
    float4v* dst = (float4v*)&xs[0][0];
    dst[tid] = src[tid];
    dst[tid + 256] = src[tid + 256];
  }
  float a20;
  bool fast = a_fast(alog, d, a20);
  const size_t H = (size_t)B_ * NCHUNK * DI * NST;
  size_t cidx = ((size_t)(b * NCHUNK + c) * DI + d) * NST;
  f32x2 h2[8];
#pragma unroll
  for (int q = 0; q < 8; ++q) h2[q] = *(const f32x2*)&chk[H + cidx + 2 * q];
  float Dv = dvec[d];
  __syncthreads();
  size_t ubase = ((size_t)b * L_ + t0) * DI + d;
  size_t zbase = ((size_t)b * L_ + t0) * (2 * DI) + DI + d;
  if (fast) {
    for (int t = 0; t < CLEN; ++t) {
      float dtv = dtf[ubase];
      float uv  = bf2f(uh[ubase]);
      float du  = dtv * uv;
      float p1 = exp2f(dtv * a20);
      float p2 = p1 * p1;
      f32x2 pw = {p1, p2};
      f32x2 pst = {p2, p2};
      f32x2 du2 = {du, du};
      f32x2 acc2 = {0.f, 0.f};
#pragma unroll
      for (int k = 0; k < 4; ++k) {
        f32x4 bv = *(const f32x4*)&xs[t][DTR + k * 4];
        f32x4 cv = *(const f32x4*)&xs[t][DTR + NST + k * 4];
        f32x2 blo = __builtin_shufflevector(bv, bv, 0, 1);
        f32x2 bhi = __builtin_shufflevector(bv, bv, 2, 3);
        f32x2 clo = __builtin_shufflevector(cv, cv, 0, 1);
        f32x2 chi = __builtin_shufflevector(cv, cv, 2, 3);
        h2[2 * k]     = pk_fma(pw, h2[2 * k], pk_mul(du2, blo));
        acc2          = pk_fma(h2[2 * k], clo, acc2);
        pw = pk_mul(pw, pst);
        h2[2 * k + 1] = pk_fma(pw, h2[2 * k + 1], pk_mul(du2, bhi));
        acc2          = pk_fma(h2[2 * k + 1], chi, acc2);
        if (k < 3) pw = pk_mul(pw, pst);
      }
      float y = acc2.x + acc2.y + uv * Dv;
      float z = bf2f(xz[zbase]);
      yg[ubase] = f2bf(y * z * sigmoidf_(z));
      ubase += DI; zbase += 2 * DI;
    }
  } else {
    float A2[NST];
#pragma unroll
    for (int n = 0; n < NST; ++n) A2[n] = -__expf(alog[d * NST + n]) * LN2R;
    for (int t = 0; t < CLEN; ++t) {
      float dtv = dtf[ubase];
      float uv  = bf2f(uh[ubase]);
      float du  = dtv * uv;
      f32x2 acc2 = {0.f, 0.f};
#pragma unroll
      for (int q = 0; q < 8; ++q) {
        f32x2 bv = *(const f32x2*)&xs[t][DTR + q * 2];
        f32x2 cv = *(const f32x2*)&xs[t][DTR + NST + q * 2];
        f32x2 e = {exp2f(dtv * A2[2 * q]), exp2f(dtv * A2[2 * q + 1])};
        h2[q] = pk_fma(e, h2[q], pk_mul((f32x2){du, du}, bv));
        acc2 = pk_fma(h2[q], cv, acc2);
      }
      float y = acc2.x + acc2.y + uv * Dv;
      float z = bf2f(xz[zbase]);
      yg[ubase] = f2bf(y * z * sigmoidf_(z));
      ubase += DI; zbase += 2 * DI;
    }
  }
}

// ---------------- final rmsnorm(hid+res) -> concat buffer (with flip for dir 1) ----------------
__global__ __launch_bounds__(256) void fincat_k(const float* __restrict__ hid,
                                                const float* __restrict__ res,
                                                const float* __restrict__ w,
                                                u16* __restrict__ cat, int dir) {
  int row = blockIdx.x;
  int tid = threadIdx.x;
  int base = row * DM;
  float x0 = hid[base + tid] + res[base + tid];
  float x1 = hid[base + 256 + tid] + res[base + 256 + tid];
  float s = x0 * x0 + x1 * x1;
  for (int off = 32; off; off >>= 1) s += __shfl_xor(s, off);
  __shared__ float ps[4];
  if (!(tid & 63)) ps[tid >> 6] = s;
  __syncthreads();
  float tot = ps[0] + ps[1] + ps[2] + ps[3];
  float rs = 1.f / sqrtf(tot / (float)DM + 1e-5f);
  int b = row >> 11, l = row & (L_ - 1);
  size_t drow = dir ? ((size_t)(b << 11) + (L_ - 1 - l)) : (size_t)row;
  size_t obase = drow * (2 * DM) + (size_t)dir * DM;
  cat[obase + tid]       = f2bf(x0 * rs * w[tid]);
  cat[obase + 256 + tid] = f2bf(x1 * rs * w[tid + 256]);
}

extern "C" void kernel_launch(void* const* d_in, const int* in_sizes, int n_in,
                              void* d_out, int out_size, void* d_ws, size_t ws_size,
                              hipStream_t stream) {
  const int*   ids      = (const int*)d_in[0];
  const float* embed    = (const float*)d_in[2];
  const float* in_w     = (const float*)d_in[3];
  const float* conv_w   = (const float*)d_in[4];
  const float* conv_b   = (const float*)d_in[5];
  const float* x_w      = (const float*)d_in[6];
  const float* dt_w     = (const float*)d_in[7];
  const float* dt_bias  = (const float*)d_in[8];
  const float* A_log    = (const float*)d_in[9];
  const float* Dp       = (const float*)d_in[10];
  const float* out_w    = (const float*)d_in[11];
  const float* norm_w   = (const float*)d_in[12];
  const float* norm_f   = (const float*)d_in[13];
  const float* proj_w   = (const float*)d_in[14];
  const float* proj_b   = (const float*)d_in[15];

  char* ws = (char*)d_ws;
  size_t off = 0;
  auto alloc = [&](size_t bytes) {
    void* p = ws + off;
    off += (bytes + 255) & ~(size_t)255;
    return p;
  };
  float* res  = (float*)alloc((size_t)ROWS * DM * 4);        // 16.8 MB
  float* hid  = (float*)alloc((size_t)ROWS * DM * 4);        // 16.8 MB
  u16*   xnyg = (u16*)alloc((size_t)ROWS * DI * 2);          // 16.8 MB (xn | yg)
  u16*   xz   = (u16*)alloc((size_t)ROWS * 2 * DI * 2);      // 33.6 MB
  u16*   u_h  = (u16*)alloc((size_t)ROWS * DI * 2);          // 16.8 MB
  float* xdbl = (float*)alloc((size_t)ROWS * 64 * 4);        //  2.1 MB
  float* dtf  = (float*)alloc((size_t)ROWS * DI * 4);        // 33.6 MB
  float* chk  = (float*)alloc((size_t)2 * B_ * NCHUNK * DI * NST * 4);  // 33.6 MB
  u16*   cat  = (u16*)alloc((size_t)ROWS * 2 * DM * 2);      // 16.8 MB
  const int N_IN  = 4 * 2 * DI * DM;   // 4,194,304
  const int N_XW  = 4 * 64 * DI;       //   262,144
  const int N_OW  = 4 * DM * DI;       // 2,097,152
  const int N_PW  = DM * 2 * DM;       //   524,288
  const int N_DTW = 4 * DTR * DI;      //   131,072
  u16*   in_wb  = (u16*)alloc((size_t)N_IN * 2);             //  8.4 MB
  u16*   x_wb   = (u16*)alloc((size_t)N_XW * 2);             //  0.5 MB
  u16*   out_wb = (u16*)alloc((size_t)N_OW * 2);             //  4.2 MB
  u16*   pr_wb  = (u16*)alloc((size_t)N_PW * 2);             //  1.0 MB
  float* dtw_t  = (float*)alloc((size_t)N_DTW * 4);          //  0.5 MB
  if (off > ws_size) return;

  cvt_k<<<(N_IN / 4 + 255) / 256, 256, 0, stream>>>(in_w, in_wb, N_IN / 4);
  cvt_k<<<(N_XW / 4 + 255) / 256, 256, 0, stream>>>(x_w, x_wb, N_XW / 4);
  cvt_k<<<(N_OW / 4 + 255) / 256, 256, 0, stream>>>(out_w, out_wb, N_OW / 4);
  cvt_k<<<(N_PW / 4 + 255) / 256, 256, 0, stream>>>(proj_w, pr_wb, N_PW / 4);
  trp_k<<<N_DTW / 256, 256, 0, stream>>>(dt_w, dtw_t);

  for (int d = 0; d < 2; ++d) {
    embed_k<<<ROWS * DM / 256, 256, 0, stream>>>(ids, embed + (size_t)d * 128 * DM, res, d);
    for (int i = 0; i < 2; ++i) {
      int li = d * 2 + i;
      if (i == 0)
        addnorm_k<false><<<ROWS, 256, 0, stream>>>(res, hid, norm_w + (size_t)li * DM, xnyg);
      else
        addnorm_k<true><<<ROWS, 256, 0, stream>>>(res, hid, norm_w + (size_t)li * DM, xnyg);
      gemm_bt<128, EPI_BF16><<<dim3(ROWS / 128, 16), 256, 0, stream>>>(
          xnyg, in_wb + (size_t)li * 2 * DI * DM, xz, nullptr, 2 * DI, DM);
      conv_k<<<ROWS * DI / 256, 256, 0, stream>>>(
          xz, conv_w + (size_t)li * DI * 4, conv_b + (size_t)li * DI, u_h);
      gemm_bt<64, EPI_F32><<<dim3(ROWS / 128, 1), 256, 0, stream>>>(
          u_h, x_wb + (size_t)li * 64 * DI, xdbl, nullptr, 64, DI);
      dtk<<<dim3((ROWS / 32) * 4), 256, 0, stream>>>(
          xdbl, dtw_t + (size_t)li * DTR * DI, dt_bias + (size_t)li * DI, dtf);
      scan1_k<<<B_ * NCHUNK * (DI / 256), 256, 0, stream>>>(
          u_h, dtf, xdbl, A_log + (size_t)li * DI * NST, chk);
      scan2_k<<<(B_ * DI * NST) / 256, 256, 0, stream>>>(chk);
      scan3_k<<<B_ * NCHUNK * (DI / 256), 256, 0, stream>>>(
          u_h, dtf, xdbl, A_log + (size_t)li * DI * NST, Dp + (size_t)li * DI, chk,
          xz, xnyg);
      gemm_bt<64, EPI_F32><<<dim3(ROWS / 128, DM / 64), 256, 0, stream>>>(
          xnyg, out_wb + (size_t)li * DM * DI, hid, nullptr, DM, DI);
    }
    fincat_k<<<ROWS, 256, 0, stream>>>(hid, res, norm_f + (size_t)d * DM, cat, d);
  }
  gemm_bt<64, EPI_BIAS><<<dim3(ROWS / 128, DM / 64), 256, 0, stream>>>(
      cat, pr_wb, (float*)d_out, proj_b, DM, DI);
}

// Round 9
// 921.594 us; speedup vs baseline: 1.3982x; 1.0117x over previous
//
#include <hip/hip_runtime.h>
#include <hip/hip_bf16.h>

#define B_   4
#define L_   2048
#define DM   512
#define DI   1024
#define NST  16
#define DTR  32
#define ROWS (B_ * L_)   // 8192
#define NCHUNK 64
#define CLEN  (L_ / NCHUNK)   // 32
#define LN2R 1.4426950408889634f

typedef unsigned short u16;
typedef __attribute__((ext_vector_type(8))) short bf16x8;
typedef __attribute__((ext_vector_type(4))) float f32x4;
typedef __attribute__((ext_vector_type(4))) float float4v;
typedef __attribute__((ext_vector_type(2))) float f32x2;

__device__ __forceinline__ float bf2f(u16 h) {
  union { unsigned int u; float f; } v; v.u = ((unsigned int)h) << 16; return v.f;
}
__device__ __forceinline__ u16 f2bf(float f) {
  union { float f; unsigned int u; } v; v.f = f;
  unsigned int u = v.u;
  if ((u & 0x7fffffffu) > 0x7f800000u) return (u16)((u >> 16) | 0x0040u);
  return (u16)((u + 0x7fffu + ((u >> 16) & 1u)) >> 16);
}
__device__ __forceinline__ float sigmoidf_(float x) { return 1.f / (1.f + __expf(-x)); }

// packed f32 ops (MI355X full-rate fp32 = v_pk_*_f32)
__device__ __forceinline__ f32x2 pk_mul(f32x2 a, f32x2 b) {
  f32x2 d; asm("v_pk_mul_f32 %0, %1, %2" : "=v"(d) : "v"(a), "v"(b)); return d;
}
__device__ __forceinline__ f32x2 pk_fma(f32x2 a, f32x2 b, f32x2 c) {
  f32x2 d; asm("v_pk_fma_f32 %0, %1, %2, %3" : "=v"(d) : "v"(a), "v"(b), "v"(c)); return d;
}

// async global->LDS, 16B per lane; dest = wave-uniform base + lane*16 (m97 pattern)
__device__ __forceinline__ void gload16(const u16* g, u16* l) {
  __builtin_amdgcn_global_load_lds(
      (const __attribute__((address_space(1))) void*)g,
      (__attribute__((address_space(3))) void*)l, 16, 0, 0);
}

// ---------------- f32 -> bf16 weight conversion ----------------
__global__ __launch_bounds__(256) void cvt_k(const float* __restrict__ in,
                                             u16* __restrict__ out, int n4) {
  int i = blockIdx.x * 256 + threadIdx.x;       // n4 = n/4
  if (i >= n4) return;
  float4v v = *(const float4v*)&in[i * 4];
  u16 o[4];
  o[0] = f2bf(v.x); o[1] = f2bf(v.y); o[2] = f2bf(v.z); o[3] = f2bf(v.w);
  *(ulong1*)&out[i * 4] = *(ulong1*)o;
}

// ---------------- dt_w transpose: [4][DI][DTR] -> [4][DTR][DI] (f32) ----------------
__global__ __launch_bounds__(256) void trp_k(const float* __restrict__ in,
                                             float* __restrict__ out) {
  int o = blockIdx.x * 256 + threadIdx.x;       // 4*DTR*DI = 131072
  int li = o >> 15;
  int k = (o >> 10) & (DTR - 1);
  int d = o & (DI - 1);
  out[o] = in[((size_t)li * DI + d) * DTR + k];
}

// ---------------- embed gather (writes f32 residual) ----------------
__global__ __launch_bounds__(256) void embed_k(const int* __restrict__ ids,
                                               const float* __restrict__ emb,
                                               float* __restrict__ res, int flip) {
  int idx = blockIdx.x * 256 + threadIdx.x;         // ROWS*DM threads
  int c = idx & (DM - 1);
  int row = idx >> 9;
  int b = row >> 11;
  int l = row & (L_ - 1);
  int sl = flip ? (L_ - 1 - l) : l;
  int id = ids[(b << 11) + sl];
  res[idx] = emb[id * DM + c];
}

// ---------------- (res += hid); xn = rmsnorm(res) * w  (bf16 out) ----------------
template <bool ADD>
__global__ __launch_bounds__(256) void addnorm_k(float* __restrict__ res,
                                                 const float* __restrict__ hid,
                                                 const float* __restrict__ w,
                                                 u16* __restrict__ xn) {
  int row = blockIdx.x;
  int tid = threadIdx.x;
  int base = row * DM;
  float x0 = res[base + tid];
  float x1 = res[base + 256 + tid];
  if (ADD) {
    x0 += hid[base + tid];
    x1 += hid[base + 256 + tid];
    res[base + tid] = x0;
    res[base + 256 + tid] = x1;
  }
  float s = x0 * x0 + x1 * x1;
  for (int off = 32; off; off >>= 1) s += __shfl_xor(s, off);
  __shared__ float ps[4];
  if (!(tid & 63)) ps[tid >> 6] = s;
  __syncthreads();
  float tot = ps[0] + ps[1] + ps[2] + ps[3];
  float rs = 1.f / sqrtf(tot / (float)DM + 1e-5f);
  xn[base + tid]       = f2bf(x0 * rs * w[tid]);
  xn[base + 256 + tid] = f2bf(x1 * rs * w[tid + 256]);
}

// ---------------- GEMM: out[m][n] = sum_k A[m][k] * W[n][k] ----------------
// 2-phase double-buffered staging, counted vmcnt, raw barriers (T3/T4 minimum recipe).
#define EPI_F32  0
#define EPI_BF16 1
#define EPI_BIAS 2

template <int BN, int EPI>
__global__ __launch_bounds__(256) void gemm_bt(const u16* __restrict__ A,
                                               const u16* __restrict__ W,
                                               void* __restrict__ outp,
                                               const float* __restrict__ bias,
                                               int N, int K) {
  constexpr int BM = 128, BK = 32;
  constexpr int NF = BN / 32;                       // n-frags per wave
  constexpr int G = (BM + BN) * BK * 2 / (256 * 16); // gloads per thread per stage (4 or 3)
  __shared__ u16 As[2][BM * BK];                    // 2 x 8 kB
  __shared__ u16 Wsh[2][BN * BK];
  int tid = threadIdx.x;
  int lane = tid & 63;
  int wv = tid >> 6;
  int wr = wv >> 1, wc = wv & 1;
  int m0 = blockIdx.x * BM, n0 = blockIdx.y * BN;
  f32x4 acc[4][NF];
#pragma unroll
  for (int i = 0; i < 4; ++i)
#pragma unroll
    for (int j = 0; j < NF; ++j) acc[i][j] = (f32x4){0.f, 0.f, 0.f, 0.f};
  int rr = lane & 15;
  int kk = (lane >> 4) << 3;
  int l4 = lane >> 2;          // 0..15: row within 16-row chunk
  int c8 = (lane & 3) << 3;    // 0,8,16,24: k-col (u16)
  const u16* Ag = A + (size_t)(m0 + l4) * K + c8;
  const u16* Wg = W + (size_t)(n0 + l4) * K + c8;

  auto stage = [&](int k0, int buf) {
    gload16(Ag + (size_t)(wv * 16) * K + k0, &As[buf][wv * 512]);
    gload16(Ag + (size_t)((wv + 4) * 16) * K + k0, &As[buf][(wv + 4) * 512]);
    gload16(Wg + (size_t)(wv * 16) * K + k0, &Wsh[buf][wv * 512]);
    if (BN == 128)
      gload16(Wg + (size_t)((wv + 4) * 16) * K + k0, &Wsh[buf][(wv + 4) * 512]);
  };

  int NK = K / BK;
  stage(0, 0);
  for (int k = 0; k < NK; ++k) {
    int cur = k & 1;
    if (k + 1 < NK) {
      stage((k + 1) * BK, cur ^ 1);
      // wait for buf[cur]'s loads (oldest); the G just-issued stay in flight
      asm volatile("s_waitcnt vmcnt(%0)" :: "n"(G) : "memory");
    } else {
      asm volatile("s_waitcnt vmcnt(0)" ::: "memory");
    }
    __builtin_amdgcn_s_barrier();
    __builtin_amdgcn_sched_barrier(0);
    bf16x8 af[4], wf[NF];
#pragma unroll
    for (int mi = 0; mi < 4; ++mi)
      af[mi] = *(bf16x8*)&As[cur][(wr * 64 + mi * 16 + rr) * BK + kk];
#pragma unroll
    for (int ni = 0; ni < NF; ++ni)
      wf[ni] = *(bf16x8*)&Wsh[cur][(wc * (BN / 2) + ni * 16 + rr) * BK + kk];
#pragma unroll
    for (int mi = 0; mi < 4; ++mi)
#pragma unroll
      for (int ni = 0; ni < NF; ++ni)
        acc[mi][ni] = __builtin_amdgcn_mfma_f32_16x16x32_bf16(af[mi], wf[ni], acc[mi][ni], 0, 0, 0);
    // all waves done reading buf[cur] before next iter overwrites it
    asm volatile("s_waitcnt lgkmcnt(0)" ::: "memory");
    __builtin_amdgcn_s_barrier();
  }
  // C/D layout: col = lane&15, row = (lane>>4)*4 + j
  int cr = (lane >> 4) << 2;
  int cc = lane & 15;
#pragma unroll
  for (int mi = 0; mi < 4; ++mi)
#pragma unroll
    for (int ni = 0; ni < NF; ++ni) {
      int row = m0 + wr * 64 + mi * 16 + cr;
      int col = n0 + wc * (BN / 2) + ni * 16 + cc;
      float bv = (EPI == EPI_BIAS) ? bias[col] : 0.f;
#pragma unroll
      for (int j = 0; j < 4; ++j) {
        float v = acc[mi][ni][j] + bv;
        if (EPI == EPI_BF16)
          ((u16*)outp)[(size_t)(row + j) * N + col] = f2bf(v);
        else
          ((float*)outp)[(size_t)(row + j) * N + col] = v;
      }
    }
}

// ---------------- depthwise causal conv (k=4) + bias + SiLU (bf16 out) ----------------
__global__ __launch_bounds__(256) void conv_k(const u16* __restrict__ xz,
                                              const float* __restrict__ cw,
                                              const float* __restrict__ cb,
                                              u16* __restrict__ uh) {
  int idx = blockIdx.x * 256 + threadIdx.x;        // ROWS*DI
  int c = idx & (DI - 1);
  int row = idx >> 10;
  int l = row & (L_ - 1);
  float acc = cb[c];
#pragma unroll
  for (int j = 0; j < 4; ++j) {
    int ls = l + j - 3;
    if (ls >= 0)
      acc += bf2f(xz[(size_t)(row + j - 3) * (2 * DI) + c]) * cw[c * 4 + j];
  }
  float s = acc * sigmoidf_(acc);
  uh[idx] = f2bf(s);
}

// ---------------- dt = softplus(xdbl[:, :32] @ dtw^T + dtb), f32 out ----------------
__global__ __launch_bounds__(256) void dtk(const float* __restrict__ xdbl,
                                           const float* __restrict__ dtw_t,
                                           const float* __restrict__ dtb,
                                           float* __restrict__ dtf) {
  __shared__ float xs[32][DTR];                   // 4 kB: 32 rows of x
  int rg = blockIdx.x >> 2;                       // row group (32 rows)
  int cg = blockIdx.x & 3;
  int tid = threadIdx.x;
  int c = cg * 256 + tid;
  {
    int r = tid >> 3, kk = (tid & 7) << 2;
    *(float4v*)&xs[r][kk] = *(const float4v*)&xdbl[(size_t)(rg * 32 + r) * 64 + kk];
  }
  float w[DTR];
#pragma unroll
  for (int k = 0; k < DTR; ++k) w[k] = dtw_t[(size_t)k * DI + c];
  float bias = dtb[c];
  __syncthreads();
#pragma unroll 4
  for (int r = 0; r < 32; ++r) {
    float a = bias;
#pragma unroll
    for (int k4 = 0; k4 < 8; ++k4) {
      float4v xv = *(const float4v*)&xs[r][k4 * 4];
      a += xv.x * w[k4 * 4] + xv.y * w[k4 * 4 + 1] + xv.z * w[k4 * 4 + 2] + xv.w * w[k4 * 4 + 3];
    }
    float sp = (a > 15.f) ? a : __logf(1.f + __expf(a));
    dtf[(size_t)(rg * 32 + r) * DI + c] = sp;
  }
}

// A-structure check: A[n] == (n+1)*A[0] (true for A_log = log(1..16))
__device__ __forceinline__ bool a_fast(const float* alog, int d, float& a20) {
  a20 = -__expf(alog[d * NST]) * LN2R;
  bool fast = true;
#pragma unroll
  for (int n = 1; n < NST; ++n) {
    float an = -__expf(alog[d * NST + n]) * LN2R;
    fast &= (fabsf(an - (float)(n + 1) * a20) <= 1e-5f * (float)(n + 1) * fabsf(a20));
  }
  return fast;
}

// ---------------- chunk-parallel selective scan ----------------
// pass 1: local scan from h=0 over chunk -> store decay + local end state
__global__ __launch_bounds__(256) void scan1_k(const u16* __restrict__ uh,
                                               const float* __restrict__ dtf,
                                               const float* __restrict__ xdbl,
                                               const float* __restrict__ alog,
                                               float* __restrict__ chk) {
  __shared__ float xs[CLEN][64];                  // 8 kB
  int blk = blockIdx.x;            // B*NCHUNK*(DI/256) = 1024
  int db = blk & 3;
  int c  = (blk >> 2) & (NCHUNK - 1);
  int b  = blk >> 8;
  int tid = threadIdx.x;
  int d  = db * 256 + tid;
  int t0 = c * CLEN;
  {
    const float4v* src = (const float4v*)(xdbl + ((size_t)b * L_ + t0) * 64);
    float4v* dst = (float4v*)&xs[0][0];
    dst[tid] = src[tid];
    dst[tid + 256] = src[tid + 256];
  }
  float a20;
  bool fast = a_fast(alog, d, a20);
  __syncthreads();
  float S = 0.f;
  size_t ubase = ((size_t)b * L_ + t0) * DI + d;
  f32x2 h2[8];
#pragma unroll
  for (int q = 0; q < 8; ++q) h2[q] = (f32x2){0.f, 0.f};
  if (fast) {
    for (int t = 0; t < CLEN; ++t) {
      float dtv = dtf[ubase];
      float du  = dtv * bf2f(uh[ubase]);
      S += dtv;
      float p1 = exp2f(dtv * a20);
      float p2 = p1 * p1;
      f32x2 pw = {p1, p2};
      f32x2 pst = {p2, p2};
      f32x2 du2 = {du, du};
#pragma unroll
      for (int k = 0; k < 4; ++k) {
        f32x4 bv = *(const f32x4*)&xs[t][DTR + k * 4];
        f32x2 blo = __builtin_shufflevector(bv, bv, 0, 1);
        f32x2 bhi = __builtin_shufflevector(bv, bv, 2, 3);
        h2[2 * k]     = pk_fma(pw, h2[2 * k], pk_mul(du2, blo));
        pw = pk_mul(pw, pst);
        h2[2 * k + 1] = pk_fma(pw, h2[2 * k + 1], pk_mul(du2, bhi));
        if (k < 3) pw = pk_mul(pw, pst);
      }
      ubase += DI;
    }
  } else {
    float A2[NST];
#pragma unroll
    for (int n = 0; n < NST; ++n) A2[n] = -__expf(alog[d * NST + n]) * LN2R;
    for (int t = 0; t < CLEN; ++t) {
      float dtv = dtf[ubase];
      float du  = dtv * bf2f(uh[ubase]);
      S += dtv;
#pragma unroll
      for (int q = 0; q < 8; ++q) {
        f32x2 bv = *(const f32x2*)&xs[t][DTR + q * 2];
        f32x2 e = {exp2f(dtv * A2[2 * q]), exp2f(dtv * A2[2 * q + 1])};
        h2[q] = pk_fma(e, h2[q], pk_mul((f32x2){du, du}, bv));
      }
      ubase += DI;
    }
  }
  const size_t H = (size_t)B_ * NCHUNK * DI * NST;
  size_t idx = ((size_t)(b * NCHUNK + c) * DI + d) * NST;
#pragma unroll
  for (int n = 0; n < NST; ++n) {
    float an = -__expf(alog[d * NST + n]) * LN2R;
    chk[idx + n]     = exp2f(an * S);
    chk[H + idx + n] = (n & 1) ? h2[n >> 1].y : h2[n >> 1].x;
  }
}

// pass 2: per (b,d,n): sequential combine over chunks; overwrite chk_h with start states
__global__ __launch_bounds__(256) void scan2_k(float* __restrict__ chk) {
  int j = blockIdx.x * 256 + threadIdx.x;   // 65536 = B*DI*NST
  int n = j & 15;
  int d = (j >> 4) & (DI - 1);
  int b = j >> 14;
  const size_t H = (size_t)B_ * NCHUNK * DI * NST;
  float h = 0.f;
  for (int c = 0; c < NCHUNK; ++c) {
    size_t idx = ((size_t)(b * NCHUNK + c) * DI + d) * NST + n;
    float a = chk[idx];
    float hl = chk[H + idx];
    chk[H + idx] = h;               // start state for this chunk
    h = a * h + hl;
  }
}

// pass 3: re-run chunk from true start state; fused gate -> bf16 yg
__global__ __launch_bounds__(256) void scan3_k(const u16* __restrict__ uh,
                                               const float* __restrict__ dtf,
                                               const float* __restrict__ xdbl,
                                               const float* __restrict__ alog,
                                               const float* __restrict__ dvec,
                                               const float* __restrict__ chk,
                                               const u16* __restrict__ xz,
                                               u16* __restrict__ yg) {
  __shared__ float xs[CLEN][64];                  // 8 kB
  int blk = blockIdx.x;            // 1024
  int db = blk & 3;
  int c  = (blk >> 2) & (NCHUNK - 1);
  int b  = blk >> 8;
  int tid = threadIdx.x;
  int d  = db * 256 + tid;
  int t0 = c * CLEN;
  {
    const float4v* src = (const float4v*)(xdbl + ((size_t)b * L_ + t0) * 64);
    float4v* dst = (float4v*)&xs[0][0];
    dst[tid] = src[tid];
    dst[tid + 256] = src[tid + 256];
  }
  float a20;
  bool fast = a_fast(alog, d, a20);
  const size_t H = (size_t)B_ * NCHUNK * DI * NST;
  size_t cidx = ((size_t)(b * NCHUNK + c) * DI + d) * NST;
  f32x2 h2[8];
#pragma unroll
  for (int q = 0; q < 8; ++q) h2[q] = *(const f32x2*)&chk[H + cidx + 2 * q];
  float Dv = dvec[d];
  __syncthreads();
  size_t ubase = ((size_t)b * L_ + t0) * DI + d;
  size_t zbase = ((size_t)b * L_ + t0) * (2 * DI) + DI + d;
  if (fast) {
    for (int t = 0; t < CLEN; ++t) {
      float dtv = dtf[ubase];
      float uv  = bf2f(uh[ubase]);
      float du  = dtv * uv;
      float p1 = exp2f(dtv * a20);
      float p2 = p1 * p1;
      f32x2 pw = {p1, p2};
      f32x2 pst = {p2, p2};
      f32x2 du2 = {du, du};
      f32x2 acc2 = {0.f, 0.f};
#pragma unroll
      for (int k = 0; k < 4; ++k) {
        f32x4 bv = *(const f32x4*)&xs[t][DTR + k * 4];
        f32x4 cv = *(const f32x4*)&xs[t][DTR + NST + k * 4];
        f32x2 blo = __builtin_shufflevector(bv, bv, 0, 1);
        f32x2 bhi = __builtin_shufflevector(bv, bv, 2, 3);
        f32x2 clo = __builtin_shufflevector(cv, cv, 0, 1);
        f32x2 chi = __builtin_shufflevector(cv, cv, 2, 3);
        h2[2 * k]     = pk_fma(pw, h2[2 * k], pk_mul(du2, blo));
        acc2          = pk_fma(h2[2 * k], clo, acc2);
        pw = pk_mul(pw, pst);
        h2[2 * k + 1] = pk_fma(pw, h2[2 * k + 1], pk_mul(du2, bhi));
        acc2          = pk_fma(h2[2 * k + 1], chi, acc2);
        if (k < 3) pw = pk_mul(pw, pst);
      }
      float y = acc2.x + acc2.y + uv * Dv;
      float z = bf2f(xz[zbase]);
      yg[ubase] = f2bf(y * z * sigmoidf_(z));
      ubase += DI; zbase += 2 * DI;
    }
  } else {
    float A2[NST];
#pragma unroll
    for (int n = 0; n < NST; ++n) A2[n] = -__expf(alog[d * NST + n]) * LN2R;
    for (int t = 0; t < CLEN; ++t) {
      float dtv = dtf[ubase];
      float uv  = bf2f(uh[ubase]);
      float du  = dtv * uv;
      f32x2 acc2 = {0.f, 0.f};
#pragma unroll
      for (int q = 0; q < 8; ++q) {
        f32x2 bv = *(const f32x2*)&xs[t][DTR + q * 2];
        f32x2 cv = *(const f32x2*)&xs[t][DTR + NST + q * 2];
        f32x2 e = {exp2f(dtv * A2[2 * q]), exp2f(dtv * A2[2 * q + 1])};
        h2[q] = pk_fma(e, h2[q], pk_mul((f32x2){du, du}, bv));
        acc2 = pk_fma(h2[q], cv, acc2);
      }
      float y = acc2.x + acc2.y + uv * Dv;
      float z = bf2f(xz[zbase]);
      yg[ubase] = f2bf(y * z * sigmoidf_(z));
      ubase += DI; zbase += 2 * DI;
    }
  }
}

// ---------------- final rmsnorm(hid+res) -> concat buffer (with flip for dir 1) ----------------
__global__ __launch_bounds__(256) void fincat_k(const float* __restrict__ hid,
                                                const float* __restrict__ res,
                                                const float* __restrict__ w,
                                                u16* __restrict__ cat, int dir) {
  int row = blockIdx.x;
  int tid = threadIdx.x;
  int base = row * DM;
  float x0 = hid[base + tid] + res[base + tid];
  float x1 = hid[base + 256 + tid] + res[base + 256 + tid];
  float s = x0 * x0 + x1 * x1;
  for (int off = 32; off; off >>= 1) s += __shfl_xor(s, off);
  __shared__ float ps[4];
  if (!(tid & 63)) ps[tid >> 6] = s;
  __syncthreads();
  float tot = ps[0] + ps[1] + ps[2] + ps[3];
  float rs = 1.f / sqrtf(tot / (float)DM + 1e-5f);
  int b = row >> 11, l = row & (L_ - 1);
  size_t drow = dir ? ((size_t)(b << 11) + (L_ - 1 - l)) : (size_t)row;
  size_t obase = drow * (2 * DM) + (size_t)dir * DM;
  cat[obase + tid]       = f2bf(x0 * rs * w[tid]);
  cat[obase + 256 + tid] = f2bf(x1 * rs * w[tid + 256]);
}

extern "C" void kernel_launch(void* const* d_in, const int* in_sizes, int n_in,
                              void* d_out, int out_size, void* d_ws, size_t ws_size,
                              hipStream_t stream) {
  const int*   ids      = (const int*)d_in[0];
  const float* embed    = (const float*)d_in[2];
  const float* in_w     = (const float*)d_in[3];
  const float* conv_w   = (const float*)d_in[4];
  const float* conv_b   = (const float*)d_in[5];
  const float* x_w      = (const float*)d_in[6];
  const float* dt_w     = (const float*)d_in[7];
  const float* dt_bias  = (const float*)d_in[8];
  const float* A_log    = (const float*)d_in[9];
  const float* Dp       = (const float*)d_in[10];
  const float* out_w    = (const float*)d_in[11];
  const float* norm_w   = (const float*)d_in[12];
  const float* norm_f   = (const float*)d_in[13];
  const float* proj_w   = (const float*)d_in[14];
  const float* proj_b   = (const float*)d_in[15];

  char* ws = (char*)d_ws;
  size_t off = 0;
  auto alloc = [&](size_t bytes) {
    void* p = ws + off;
    off += (bytes + 255) & ~(size_t)255;
    return p;
  };
  float* res  = (float*)alloc((size_t)ROWS * DM * 4);        // 16.8 MB
  float* hid  = (float*)alloc((size_t)ROWS * DM * 4);        // 16.8 MB
  u16*   xnyg = (u16*)alloc((size_t)ROWS * DI * 2);          // 16.8 MB (xn | yg)
  u16*   xz   = (u16*)alloc((size_t)ROWS * 2 * DI * 2);      // 33.6 MB
  u16*   u_h  = (u16*)alloc((size_t)ROWS * DI * 2);          // 16.8 MB
  float* xdbl = (float*)alloc((size_t)ROWS * 64 * 4);        //  2.1 MB
  float* dtf  = (float*)alloc((size_t)ROWS * DI * 4);        // 33.6 MB
  float* chk  = (float*)alloc((size_t)2 * B_ * NCHUNK * DI * NST * 4);  // 33.6 MB
  u16*   cat  = (u16*)alloc((size_t)ROWS * 2 * DM * 2);      // 16.8 MB
  const int N_IN  = 4 * 2 * DI * DM;   // 4,194,304
  const int N_XW  = 4 * 64 * DI;       //   262,144
  const int N_OW  = 4 * DM * DI;       // 2,097,152
  const int N_PW  = DM * 2 * DM;       //   524,288
  const int N_DTW = 4 * DTR * DI;      //   131,072
  u16*   in_wb  = (u16*)alloc((size_t)N_IN * 2);             //  8.4 MB
  u16*   x_wb   = (u16*)alloc((size_t)N_XW * 2);             //  0.5 MB
  u16*   out_wb = (u16*)alloc((size_t)N_OW * 2);             //  4.2 MB
  u16*   pr_wb  = (u16*)alloc((size_t)N_PW * 2);             //  1.0 MB
  float* dtw_t  = (float*)alloc((size_t)N_DTW * 4);          //  0.5 MB
  if (off > ws_size) return;

  cvt_k<<<(N_IN / 4 + 255) / 256, 256, 0, stream>>>(in_w, in_wb, N_IN / 4);
  cvt_k<<<(N_XW / 4 + 255) / 256, 256, 0, stream>>>(x_w, x_wb, N_XW / 4);
  cvt_k<<<(N_OW / 4 + 255) / 256, 256, 0, stream>>>(out_w, out_wb, N_OW / 4);
  cvt_k<<<(N_PW / 4 + 255) / 256, 256, 0, stream>>>(proj_w, pr_wb, N_PW / 4);
  trp_k<<<N_DTW / 256, 256, 0, stream>>>(dt_w, dtw_t);

  for (int d = 0; d < 2; ++d) {
    embed_k<<<ROWS * DM / 256, 256, 0, stream>>>(ids, embed + (size_t)d * 128 * DM, res, d);
    for (int i = 0; i < 2; ++i) {
      int li = d * 2 + i;
      if (i == 0)
        addnorm_k<false><<<ROWS, 256, 0, stream>>>(res, hid, norm_w + (size_t)li * DM, xnyg);
      else
        addnorm_k<true><<<ROWS, 256, 0, stream>>>(res, hid, norm_w + (size_t)li * DM, xnyg);
      gemm_bt<128, EPI_BF16><<<dim3(ROWS / 128, 16), 256, 0, stream>>>(
          xnyg, in_wb + (size_t)li * 2 * DI * DM, xz, nullptr, 2 * DI, DM);
      conv_k<<<ROWS * DI / 256, 256, 0, stream>>>(
          xz, conv_w + (size_t)li * DI * 4, conv_b + (size_t)li * DI, u_h);
      gemm_bt<64, EPI_F32><<<dim3(ROWS / 128, 1), 256, 0, stream>>>(
          u_h, x_wb + (size_t)li * 64 * DI, xdbl, nullptr, 64, DI);
      dtk<<<dim3((ROWS / 32) * 4), 256, 0, stream>>>(
          xdbl, dtw_t + (size_t)li * DTR * DI, dt_bias + (size_t)li * DI, dtf);
      scan1_k<<<B_ * NCHUNK * (DI / 256), 256, 0, stream>>>(
          u_h, dtf, xdbl, A_log + (size_t)li * DI * NST, chk);
      scan2_k<<<(B_ * DI * NST) / 256, 256, 0, stream>>>(chk);
      scan3_k<<<B_ * NCHUNK * (DI / 256), 256, 0, stream>>>(
          u_h, dtf, xdbl, A_log + (size_t)li * DI * NST, Dp + (size_t)li * DI, chk,
          xz, xnyg);
      gemm_bt<64, EPI_F32><<<dim3(ROWS / 128, DM / 64), 256, 0, stream>>>(
          xnyg, out_wb + (size_t)li * DM * DI, hid, nullptr, DM, DI);
    }
    fincat_k<<<ROWS, 256, 0, stream>>>(hid, res, norm_f + (size_t)d * DM, cat, d);
  }
  gemm_bt<64, EPI_BIAS><<<dim3(ROWS / 128, DM / 64), 256, 0, stream>>>(
      cat, pr_wb, (float*)d_out, proj_b, DM, DI);
}

// Round 10
// 841.453 us; speedup vs baseline: 1.5313x; 1.0952x over previous
//
#include <hip/hip_runtime.h>
#include <hip/hip_bf16.h>

#define B_   4
#define L_   2048
#define DM   512
#define DI   1024
#define NST  16
#define DTR  32
#define ROWS (B_ * L_)   // 8192
#define NCHUNK 64
#define CLEN  (L_ / NCHUNK)   // 32
#define LN2R 1.4426950408889634f

typedef unsigned short u16;
typedef __attribute__((ext_vector_type(8))) short bf16x8;
typedef __attribute__((ext_vector_type(4))) float f32x4;
typedef __attribute__((ext_vector_type(4))) float float4v;
typedef __attribute__((ext_vector_type(2))) float f32x2;

__device__ __forceinline__ float bf2f(u16 h) {
  union { unsigned int u; float f; } v; v.u = ((unsigned int)h) << 16; return v.f;
}
__device__ __forceinline__ u16 f2bf(float f) {
  union { float f; unsigned int u; } v; v.f = f;
  unsigned int u = v.u;
  if ((u & 0x7fffffffu) > 0x7f800000u) return (u16)((u >> 16) | 0x0040u);
  return (u16)((u + 0x7fffu + ((u >> 16) & 1u)) >> 16);
}
__device__ __forceinline__ float sigmoidf_(float x) { return 1.f / (1.f + __expf(-x)); }

// packed f32 ops (MI355X full-rate fp32 = v_pk_*_f32)
__device__ __forceinline__ f32x2 pk_mul(f32x2 a, f32x2 b) {
  f32x2 d; asm("v_pk_mul_f32 %0, %1, %2" : "=v"(d) : "v"(a), "v"(b)); return d;
}
__device__ __forceinline__ f32x2 pk_fma(f32x2 a, f32x2 b, f32x2 c) {
  f32x2 d; asm("v_pk_fma_f32 %0, %1, %2, %3" : "=v"(d) : "v"(a), "v"(b), "v"(c)); return d;
}

// async global->LDS, 16B per lane; dest = wave-uniform base + lane*16 (m97 pattern)
__device__ __forceinline__ void gload16(const u16* g, u16* l) {
  __builtin_amdgcn_global_load_lds(
      (const __attribute__((address_space(1))) void*)g,
      (__attribute__((address_space(3))) void*)l, 16, 0, 0);
}

// ---------------- f32 -> bf16 weight conversion ----------------
__global__ __launch_bounds__(256) void cvt_k(const float* __restrict__ in,
                                             u16* __restrict__ out, int n4) {
  int i = blockIdx.x * 256 + threadIdx.x;       // n4 = n/4
  if (i >= n4) return;
  float4v v = *(const float4v*)&in[i * 4];
  u16 o[4];
  o[0] = f2bf(v.x); o[1] = f2bf(v.y); o[2] = f2bf(v.z); o[3] = f2bf(v.w);
  *(ulong1*)&out[i * 4] = *(ulong1*)o;
}

// ---------------- dt_w transpose: [4][DI][DTR] -> [4][DTR][DI] (f32) ----------------
__global__ __launch_bounds__(256) void trp_k(const float* __restrict__ in,
                                             float* __restrict__ out) {
  int o = blockIdx.x * 256 + threadIdx.x;       // 4*DTR*DI = 131072
  int li = o >> 15;
  int k = (o >> 10) & (DTR - 1);
  int d = o & (DI - 1);
  out[o] = in[((size_t)li * DI + d) * DTR + k];
}

// ---------------- embed gather (writes f32 residual) ----------------
__global__ __launch_bounds__(256) void embed_k(const int* __restrict__ ids,
                                               const float* __restrict__ emb,
                                               float* __restrict__ res, int flip) {
  int idx = blockIdx.x * 256 + threadIdx.x;         // ROWS*DM threads
  int c = idx & (DM - 1);
  int row = idx >> 9;
  int b = row >> 11;
  int l = row & (L_ - 1);
  int sl = flip ? (L_ - 1 - l) : l;
  int id = ids[(b << 11) + sl];
  res[idx] = emb[id * DM + c];
}

// ---------------- (res += hid); xn = rmsnorm(res) * w  (bf16 out) ----------------
template <bool ADD>
__global__ __launch_bounds__(256) void addnorm_k(float* __restrict__ res,
                                                 const float* __restrict__ hid,
                                                 const float* __restrict__ w,
                                                 u16* __restrict__ xn) {
  int row = blockIdx.x;
  int tid = threadIdx.x;
  int base = row * DM;
  float x0 = res[base + tid];
  float x1 = res[base + 256 + tid];
  if (ADD) {
    x0 += hid[base + tid];
    x1 += hid[base + 256 + tid];
    res[base + tid] = x0;
    res[base + 256 + tid] = x1;
  }
  float s = x0 * x0 + x1 * x1;
  for (int off = 32; off; off >>= 1) s += __shfl_xor(s, off);
  __shared__ float ps[4];
  if (!(tid & 63)) ps[tid >> 6] = s;
  __syncthreads();
  float tot = ps[0] + ps[1] + ps[2] + ps[3];
  float rs = 1.f / sqrtf(tot / (float)DM + 1e-5f);
  xn[base + tid]       = f2bf(x0 * rs * w[tid]);
  xn[base + 256 + tid] = f2bf(x1 * rs * w[tid + 256]);
}

// ---------------- GEMM: out[m][n] = sum_k A[m][k] * W[n][k] ----------------
// 4-buffer ring, stage-ahead-3, ONE barrier per K-step, counted vmcnt.
#define EPI_F32  0
#define EPI_BF16 1
#define EPI_BIAS 2

template <int BN, int EPI, int SK = 1>
__global__ __launch_bounds__(256) void gemm_bt(const u16* __restrict__ A,
                                               const u16* __restrict__ W,
                                               void* __restrict__ outp,
                                               const float* __restrict__ bias,
                                               int N, int K) {
  constexpr int BM = 128, BK = 32;
  constexpr int NF = BN / 32;                      // n-frags per wave
  constexpr int G = (BN == 128) ? 4 : 3;           // gloads per wave per stage
  __shared__ u16 As[4][BM * BK];                   // 4 x 8 kB
  __shared__ u16 Wsh[4][BN * BK];
  int tid = threadIdx.x;
  int lane = tid & 63;
  int wv = tid >> 6;
  int wr = wv >> 1, wc = wv & 1;
  int m0 = blockIdx.x * BM;
  int n0 = (SK > 1) ? 0 : blockIdx.y * BN;
  int koff = (SK > 1) ? blockIdx.y * (K / SK) : 0;
  int KS = K / SK;
  int NK = KS / BK;
  f32x4 acc[4][NF];
#pragma unroll
  for (int i = 0; i < 4; ++i)
#pragma unroll
    for (int j = 0; j < NF; ++j) acc[i][j] = (f32x4){0.f, 0.f, 0.f, 0.f};
  int rr = lane & 15;
  int kk = (lane >> 4) << 3;
  int l4 = lane >> 2;          // 0..15: row within 16-row chunk
  int c8 = (lane & 3) << 3;    // 0,8,16,24: k-col (u16)
  const u16* Ag = A + (size_t)(m0 + l4) * K + koff + c8;
  const u16* Wg = W + (size_t)(n0 + l4) * K + koff + c8;

  auto stage = [&](int k0, int buf) {
    gload16(Ag + (size_t)(wv * 16) * K + k0, &As[buf][wv * 512]);
    gload16(Ag + (size_t)((wv + 4) * 16) * K + k0, &As[buf][(wv + 4) * 512]);
    gload16(Wg + (size_t)(wv * 16) * K + k0, &Wsh[buf][wv * 512]);
    if (BN == 128)
      gload16(Wg + (size_t)((wv + 4) * 16) * K + k0, &Wsh[buf][(wv + 4) * 512]);
  };

  stage(0, 0); stage(BK, 1); stage(2 * BK, 2);     // NK >= 8 always
  for (int k = 0; k < NK; ++k) {
    // wait for tile k (tiles k+1,k+2 stay in flight)
    if (k < NK - 2)
      asm volatile("s_waitcnt vmcnt(%0)" :: "n"(2 * G) : "memory");
    else if (k == NK - 2)
      asm volatile("s_waitcnt vmcnt(%0)" :: "n"(G) : "memory");
    else
      asm volatile("s_waitcnt vmcnt(0)" ::: "memory");
    __builtin_amdgcn_s_barrier();
    __builtin_amdgcn_sched_barrier(0);
    if (k + 3 < NK) stage((k + 3) * BK, (k + 3) & 3);
    __builtin_amdgcn_sched_barrier(0);
    int cur = k & 3;
    bf16x8 af[4], wf[NF];
#pragma unroll
    for (int mi = 0; mi < 4; ++mi)
      af[mi] = *(bf16x8*)&As[cur][(wr * 64 + mi * 16 + rr) * BK + kk];
#pragma unroll
    for (int ni = 0; ni < NF; ++ni)
      wf[ni] = *(bf16x8*)&Wsh[cur][(wc * (BN / 2) + ni * 16 + rr) * BK + kk];
#pragma unroll
    for (int mi = 0; mi < 4; ++mi)
#pragma unroll
      for (int ni = 0; ni < NF; ++ni)
        acc[mi][ni] = __builtin_amdgcn_mfma_f32_16x16x32_bf16(af[mi], wf[ni], acc[mi][ni], 0, 0, 0);
  }
  // C/D layout: col = lane&15, row = (lane>>4)*4 + j
  int cr = (lane >> 4) << 2;
  int cc = lane & 15;
  float* outF = (float*)outp + ((SK > 1) ? (size_t)blockIdx.y * (size_t)ROWS * N : 0);
#pragma unroll
  for (int mi = 0; mi < 4; ++mi)
#pragma unroll
    for (int ni = 0; ni < NF; ++ni) {
      int row = m0 + wr * 64 + mi * 16 + cr;
      int col = n0 + wc * (BN / 2) + ni * 16 + cc;
      float bv = (EPI == EPI_BIAS) ? bias[col] : 0.f;
#pragma unroll
      for (int j = 0; j < 4; ++j) {
        float v = acc[mi][ni][j] + bv;
        if (EPI == EPI_BF16)
          ((u16*)outp)[(size_t)(row + j) * N + col] = f2bf(v);
        else
          outF[(size_t)(row + j) * N + col] = v;
      }
    }
}

// ---------------- depthwise causal conv (k=4) + bias + SiLU (bf16 out) ----------------
__global__ __launch_bounds__(256) void conv_k(const u16* __restrict__ xz,
                                              const float* __restrict__ cw,
                                              const float* __restrict__ cb,
                                              u16* __restrict__ uh) {
  int idx = blockIdx.x * 256 + threadIdx.x;        // ROWS*DI
  int c = idx & (DI - 1);
  int row = idx >> 10;
  int l = row & (L_ - 1);
  float acc = cb[c];
#pragma unroll
  for (int j = 0; j < 4; ++j) {
    int ls = l + j - 3;
    if (ls >= 0)
      acc += bf2f(xz[(size_t)(row + j - 3) * (2 * DI) + c]) * cw[c * 4 + j];
  }
  float s = acc * sigmoidf_(acc);
  uh[idx] = f2bf(s);
}

// A-structure check: A[n] == (n+1)*A[0] (true for A_log = log(1..16))
__device__ __forceinline__ bool a_fast(const float* alog, int d, float& a20) {
  a20 = -__expf(alog[d * NST]) * LN2R;
  bool fast = true;
#pragma unroll
  for (int n = 1; n < NST; ++n) {
    float an = -__expf(alog[d * NST + n]) * LN2R;
    fast &= (fabsf(an - (float)(n + 1) * a20) <= 1e-5f * (float)(n + 1) * fabsf(a20));
  }
  return fast;
}

// stage xs[32][64] by summing 4 x_proj split-K partials
__device__ __forceinline__ void stage_xs(float (*xs)[64], const float* xp,
                                         int b, int t0, int tid) {
  size_t base = ((size_t)b * L_ + t0) * 64;
  const float4v* s0 = (const float4v*)(xp + base);
  const float4v* s1 = (const float4v*)(xp + (size_t)ROWS * 64 + base);
  const float4v* s2 = (const float4v*)(xp + (size_t)2 * ROWS * 64 + base);
  const float4v* s3 = (const float4v*)(xp + (size_t)3 * ROWS * 64 + base);
  float4v* dst = (float4v*)&xs[0][0];
  dst[tid]       = s0[tid]       + s1[tid]       + s2[tid]       + s3[tid];
  dst[tid + 256] = s0[tid + 256] + s1[tid + 256] + s2[tid + 256] + s3[tid + 256];
}

// ---------------- fused dt-projection + scan pass 1 ----------------
// computes dt = softplus(x@dtw^T + dtb) in-register (writes dtf for pass 3),
// then local scan from h=0 over chunk -> store decay + local end state.
__global__ __launch_bounds__(256) void dtscan1_k(const u16* __restrict__ uh,
                                                 const float* __restrict__ xp,
                                                 const float* __restrict__ dtw_t,
                                                 const float* __restrict__ dtb,
                                                 const float* __restrict__ alog,
                                                 float* __restrict__ dtf,
                                                 float* __restrict__ chk) {
  __shared__ float xs[CLEN][64];                  // 8 kB
  int blk = blockIdx.x;            // B*NCHUNK*(DI/256) = 1024
  int db = blk & 3;
  int c  = (blk >> 2) & (NCHUNK - 1);
  int b  = blk >> 8;
  int tid = threadIdx.x;
  int d  = db * 256 + tid;
  int t0 = c * CLEN;
  stage_xs(xs, xp, b, t0, tid);
  f32x2 w2[16];
#pragma unroll
  for (int j = 0; j < 16; ++j)
    w2[j] = (f32x2){dtw_t[(size_t)(2 * j) * DI + d], dtw_t[(size_t)(2 * j + 1) * DI + d]};
  float bias = dtb[d];
  float a20;
  bool fast = a_fast(alog, d, a20);
  __syncthreads();
  float S = 0.f;
  size_t ubase = ((size_t)b * L_ + t0) * DI + d;
  f32x2 h2[8];
#pragma unroll
  for (int q = 0; q < 8; ++q) h2[q] = (f32x2){0.f, 0.f};
  for (int t = 0; t < CLEN; ++t) {
    // dt projection (row xs[t][0..31] broadcast, conflict-free)
    f32x2 a2 = {bias, 0.f};
    const f32x2* xr2 = (const f32x2*)&xs[t][0];
#pragma unroll
    for (int j = 0; j < 16; ++j) a2 = pk_fma(xr2[j], w2[j], a2);
    float a = a2.x + a2.y;
    float dtv = (a > 15.f) ? a : __logf(1.f + __expf(a));
    dtf[ubase] = dtv;
    float du = dtv * bf2f(uh[ubase]);
    S += dtv;
    if (fast) {
      float p1 = exp2f(dtv * a20);
      float p2 = p1 * p1;
      f32x2 pw = {p1, p2};
      f32x2 pst = {p2, p2};
      f32x2 du2 = {du, du};
#pragma unroll
      for (int k = 0; k < 4; ++k) {
        f32x4 bv = *(const f32x4*)&xs[t][DTR + k * 4];
        f32x2 blo = __builtin_shufflevector(bv, bv, 0, 1);
        f32x2 bhi = __builtin_shufflevector(bv, bv, 2, 3);
        h2[2 * k]     = pk_fma(pw, h2[2 * k], pk_mul(du2, blo));
        pw = pk_mul(pw, pst);
        h2[2 * k + 1] = pk_fma(pw, h2[2 * k + 1], pk_mul(du2, bhi));
        if (k < 3) pw = pk_mul(pw, pst);
      }
    } else {
#pragma unroll
      for (int q = 0; q < 8; ++q) {
        float e0 = exp2f(dtv * -__expf(alog[d * NST + 2 * q]) * LN2R);
        float e1 = exp2f(dtv * -__expf(alog[d * NST + 2 * q + 1]) * LN2R);
        f32x2 bv = *(const f32x2*)&xs[t][DTR + q * 2];
        h2[q] = pk_fma((f32x2){e0, e1}, h2[q], pk_mul((f32x2){du, du}, bv));
      }
    }
    ubase += DI;
  }
  const size_t H = (size_t)B_ * NCHUNK * DI * NST;
  size_t idx = ((size_t)(b * NCHUNK + c) * DI + d) * NST;
#pragma unroll
  for (int n = 0; n < NST; ++n) {
    float an = -__expf(alog[d * NST + n]) * LN2R;
    chk[idx + n]     = exp2f(an * S);
    chk[H + idx + n] = (n & 1) ? h2[n >> 1].y : h2[n >> 1].x;
  }
}

// pass 2: per (b,d,n): sequential combine over chunks; overwrite chk_h with start states
__global__ __launch_bounds__(256) void scan2_k(float* __restrict__ chk) {
  int j = blockIdx.x * 256 + threadIdx.x;   // 65536 = B*DI*NST
  int n = j & 15;
  int d = (j >> 4) & (DI - 1);
  int b = j >> 14;
  const size_t H = (size_t)B_ * NCHUNK * DI * NST;
  float h = 0.f;
  for (int c = 0; c < NCHUNK; ++c) {
    size_t idx = ((size_t)(b * NCHUNK + c) * DI + d) * NST + n;
    float a = chk[idx];
    float hl = chk[H + idx];
    chk[H + idx] = h;               // start state for this chunk
    h = a * h + hl;
  }
}

// pass 3: re-run chunk from true start state; fused gate -> bf16 yg
__global__ __launch_bounds__(256) void scan3_k(const u16* __restrict__ uh,
                                               const float* __restrict__ dtf,
                                               const float* __restrict__ xp,
                                               const float* __restrict__ alog,
                                               const float* __restrict__ dvec,
                                               const float* __restrict__ chk,
                                               const u16* __restrict__ xz,
                                               u16* __restrict__ yg) {
  __shared__ float xs[CLEN][64];                  // 8 kB
  int blk = blockIdx.x;            // 1024
  int db = blk & 3;
  int c  = (blk >> 2) & (NCHUNK - 1);
  int b  = blk >> 8;
  int tid = threadIdx.x;
  int d  = db * 256 + tid;
  int t0 = c * CLEN;
  stage_xs(xs, xp, b, t0, tid);
  float a20;
  bool fast = a_fast(alog, d, a20);
  const size_t H = (size_t)B_ * NCHUNK * DI * NST;
  size_t cidx = ((size_t)(b * NCHUNK + c) * DI + d) * NST;
  f32x2 h2[8];
#pragma unroll
  for (int q = 0; q < 8; ++q) h2[q] = *(const f32x2*)&chk[H + cidx + 2 * q];
  float Dv = dvec[d];
  __syncthreads();
  size_t ubase = ((size_t)b * L_ + t0) * DI + d;
  size_t zbase = ((size_t)b * L_ + t0) * (2 * DI) + DI + d;
  if (fast) {
    for (int t = 0; t < CLEN; ++t) {
      float dtv = dtf[ubase];
      float uv  = bf2f(uh[ubase]);
      float du  = dtv * uv;
      float p1 = exp2f(dtv * a20);
      float p2 = p1 * p1;
      f32x2 pw = {p1, p2};
      f32x2 pst = {p2, p2};
      f32x2 du2 = {du, du};
      f32x2 acc2 = {0.f, 0.f};
#pragma unroll
      for (int k = 0; k < 4; ++k) {
        f32x4 bv = *(const f32x4*)&xs[t][DTR + k * 4];
        f32x4 cv = *(const f32x4*)&xs[t][DTR + NST + k * 4];
        f32x2 blo = __builtin_shufflevector(bv, bv, 0, 1);
        f32x2 bhi = __builtin_shufflevector(bv, bv, 2, 3);
        f32x2 clo = __builtin_shufflevector(cv, cv, 0, 1);
        f32x2 chi = __builtin_shufflevector(cv, cv, 2, 3);
        h2[2 * k]     = pk_fma(pw, h2[2 * k], pk_mul(du2, blo));
        acc2          = pk_fma(h2[2 * k], clo, acc2);
        pw = pk_mul(pw, pst);
        h2[2 * k + 1] = pk_fma(pw, h2[2 * k + 1], pk_mul(du2, bhi));
        acc2          = pk_fma(h2[2 * k + 1], chi, acc2);
        if (k < 3) pw = pk_mul(pw, pst);
      }
      float y = acc2.x + acc2.y + uv * Dv;
      float z = bf2f(xz[zbase]);
      yg[ubase] = f2bf(y * z * sigmoidf_(z));
      ubase += DI; zbase += 2 * DI;
    }
  } else {
    float A2[NST];
#pragma unroll
    for (int n = 0; n < NST; ++n) A2[n] = -__expf(alog[d * NST + n]) * LN2R;
    for (int t = 0; t < CLEN; ++t) {
      float dtv = dtf[ubase];
      float uv  = bf2f(uh[ubase]);
      float du  = dtv * uv;
      f32x2 acc2 = {0.f, 0.f};
#pragma unroll
      for (int q = 0; q < 8; ++q) {
        f32x2 bv = *(const f32x2*)&xs[t][DTR + q * 2];
        f32x2 cv = *(const f32x2*)&xs[t][DTR + NST + q * 2];
        f32x2 e = {exp2f(dtv * A2[2 * q]), exp2f(dtv * A2[2 * q + 1])};
        h2[q] = pk_fma(e, h2[q], pk_mul((f32x2){du, du}, bv));
        acc2 = pk_fma(h2[q], cv, acc2);
      }
      float y = acc2.x + acc2.y + uv * Dv;
      float z = bf2f(xz[zbase]);
      yg[ubase] = f2bf(y * z * sigmoidf_(z));
      ubase += DI; zbase += 2 * DI;
    }
  }
}

// ---------------- final rmsnorm(hid+res) -> concat buffer (with flip for dir 1) ----------------
__global__ __launch_bounds__(256) void fincat_k(const float* __restrict__ hid,
                                                const float* __restrict__ res,
                                                const float* __restrict__ w,
                                                u16* __restrict__ cat, int dir) {
  int row = blockIdx.x;
  int tid = threadIdx.x;
  int base = row * DM;
  float x0 = hid[base + tid] + res[base + tid];
  float x1 = hid[base + 256 + tid] + res[base + 256 + tid];
  float s = x0 * x0 + x1 * x1;
  for (int off = 32; off; off >>= 1) s += __shfl_xor(s, off);
  __shared__ float ps[4];
  if (!(tid & 63)) ps[tid >> 6] = s;
  __syncthreads();
  float tot = ps[0] + ps[1] + ps[2] + ps[3];
  float rs = 1.f / sqrtf(tot / (float)DM + 1e-5f);
  int b = row >> 11, l = row & (L_ - 1);
  size_t drow = dir ? ((size_t)(b << 11) + (L_ - 1 - l)) : (size_t)row;
  size_t obase = drow * (2 * DM) + (size_t)dir * DM;
  cat[obase + tid]       = f2bf(x0 * rs * w[tid]);
  cat[obase + 256 + tid] = f2bf(x1 * rs * w[tid + 256]);
}

extern "C" void kernel_launch(void* const* d_in, const int* in_sizes, int n_in,
                              void* d_out, int out_size, void* d_ws, size_t ws_size,
                              hipStream_t stream) {
  const int*   ids      = (const int*)d_in[0];
  const float* embed    = (const float*)d_in[2];
  const float* in_w     = (const float*)d_in[3];
  const float* conv_w   = (const float*)d_in[4];
  const float* conv_b   = (const float*)d_in[5];
  const float* x_w      = (const float*)d_in[6];
  const float* dt_w     = (const float*)d_in[7];
  const float* dt_bias  = (const float*)d_in[8];
  const float* A_log    = (const float*)d_in[9];
  const float* Dp       = (const float*)d_in[10];
  const float* out_w    = (const float*)d_in[11];
  const float* norm_w   = (const float*)d_in[12];
  const float* norm_f   = (const float*)d_in[13];
  const float* proj_w   = (const float*)d_in[14];
  const float* proj_b   = (const float*)d_in[15];

  char* ws = (char*)d_ws;
  size_t off = 0;
  auto alloc = [&](size_t bytes) {
    void* p = ws + off;
    off += (bytes + 255) & ~(size_t)255;
    return p;
  };
  float* res  = (float*)alloc((size_t)ROWS * DM * 4);        // 16.8 MB
  float* hid  = (float*)alloc((size_t)ROWS * DM * 4);        // 16.8 MB (x_proj partials alias)
  u16*   xnyg = (u16*)alloc((size_t)ROWS * DI * 2);          // 16.8 MB (xn | yg)
  u16*   xz   = (u16*)alloc((size_t)ROWS * 2 * DI * 2);      // 33.6 MB
  u16*   u_h  = (u16*)alloc((size_t)ROWS * DI * 2);          // 16.8 MB
  float* dtf  = (float*)alloc((size_t)ROWS * DI * 4);        // 33.6 MB
  float* chk  = (float*)alloc((size_t)2 * B_ * NCHUNK * DI * NST * 4);  // 33.6 MB
  u16*   cat  = (u16*)alloc((size_t)ROWS * 2 * DM * 2);      // 16.8 MB
  const int N_IN  = 4 * 2 * DI * DM;   // 4,194,304
  const int N_XW  = 4 * 64 * DI;       //   262,144
  const int N_OW  = 4 * DM * DI;       // 2,097,152
  const int N_PW  = DM * 2 * DM;       //   524,288
  const int N_DTW = 4 * DTR * DI;      //   131,072
  u16*   in_wb  = (u16*)alloc((size_t)N_IN * 2);             //  8.4 MB
  u16*   x_wb   = (u16*)alloc((size_t)N_XW * 2);             //  0.5 MB
  u16*   out_wb = (u16*)alloc((size_t)N_OW * 2);             //  4.2 MB
  u16*   pr_wb  = (u16*)alloc((size_t)N_PW * 2);             //  1.0 MB
  float* dtw_t  = (float*)alloc((size_t)N_DTW * 4);          //  0.5 MB
  if (off > ws_size) return;

  cvt_k<<<(N_IN / 4 + 255) / 256, 256, 0, stream>>>(in_w, in_wb, N_IN / 4);
  cvt_k<<<(N_XW / 4 + 255) / 256, 256, 0, stream>>>(x_w, x_wb, N_XW / 4);
  cvt_k<<<(N_OW / 4 + 255) / 256, 256, 0, stream>>>(out_w, out_wb, N_OW / 4);
  cvt_k<<<(N_PW / 4 + 255) / 256, 256, 0, stream>>>(proj_w, pr_wb, N_PW / 4);
  trp_k<<<N_DTW / 256, 256, 0, stream>>>(dt_w, dtw_t);

  for (int d = 0; d < 2; ++d) {
    embed_k<<<ROWS * DM / 256, 256, 0, stream>>>(ids, embed + (size_t)d * 128 * DM, res, d);
    for (int i = 0; i < 2; ++i) {
      int li = d * 2 + i;
      if (i == 0)
        addnorm_k<false><<<ROWS, 256, 0, stream>>>(res, hid, norm_w + (size_t)li * DM, xnyg);
      else
        addnorm_k<true><<<ROWS, 256, 0, stream>>>(res, hid, norm_w + (size_t)li * DM, xnyg);
      gemm_bt<128, EPI_BF16><<<dim3(ROWS / 128, 16), 256, 0, stream>>>(
          xnyg, in_wb + (size_t)li * 2 * DI * DM, xz, nullptr, 2 * DI, DM);
      conv_k<<<ROWS * DI / 256, 256, 0, stream>>>(
          xz, conv_w + (size_t)li * DI * 4, conv_b + (size_t)li * DI, u_h);
      // x_proj split-K x4: partials into hid (dead window until out_proj)
      gemm_bt<64, EPI_F32, 4><<<dim3(ROWS / 128, 4), 256, 0, stream>>>(
          u_h, x_wb + (size_t)li * 64 * DI, hid, nullptr, 64, DI);
      dtscan1_k<<<B_ * NCHUNK * (DI / 256), 256, 0, stream>>>(
          u_h, hid, dtw_t + (size_t)li * DTR * DI, dt_bias + (size_t)li * DI,
          A_log + (size_t)li * DI * NST, dtf, chk);
      scan2_k<<<(B_ * DI * NST) / 256, 256, 0, stream>>>(chk);
      scan3_k<<<B_ * NCHUNK * (DI / 256), 256, 0, stream>>>(
          u_h, dtf, hid, A_log + (size_t)li * DI * NST, Dp + (size_t)li * DI, chk,
          xz, xnyg);
      gemm_bt<64, EPI_F32><<<dim3(ROWS / 128, DM / 64), 256, 0, stream>>>(
          xnyg, out_wb + (size_t)li * DM * DI, hid, nullptr, DM, DI);
    }
    fincat_k<<<ROWS, 256, 0, stream>>>(hid, res, norm_f + (size_t)d * DM, cat, d);
  }
  gemm_bt<64, EPI_BIAS><<<dim3(ROWS / 128, DM / 64), 256, 0, stream>>>(
      cat, pr_wb, (float*)d_out, proj_b, DM, DI);
}